// Round 5
// baseline (201.176 us; speedup 1.0000x reference)
//
#include <hip/hip_runtime.h>
#include <math.h>

#define LEAK 0.01f

typedef float v2f __attribute__((ext_vector_type(2)));

__device__ __forceinline__ float lrelu(float x) { return fmaxf(x, LEAK * x); }
__device__ __forceinline__ float fast_rcp(float x) { return __builtin_amdgcn_rcpf(x); }
__device__ __forceinline__ float sigmoid_f(float x) {
    return fast_rcp(1.0f + exp2f(-1.44269504f * x));
}
__device__ __forceinline__ float tanh_f(float x) {
    return 2.0f * fast_rcp(1.0f + exp2f(-2.88539008f * x)) - 1.0f;
}
__device__ __forceinline__ float readlane_f(float v, int l) {
    return __int_as_float(__builtin_amdgcn_readlane(__float_as_int(v), l));
}

// ---- named-scalar helpers (NO arrays: guarantees SROA/register residency) ----
#define DECL5(p) v2f p##_0, p##_1, p##_2, p##_3, p##_4
#define LOAD5(p, src) do { const v2f* _s5 = (const v2f*)(src); \
    p##_0 = _s5[0]; p##_1 = _s5[1]; p##_2 = _s5[2]; p##_3 = _s5[3]; p##_4 = _s5[4]; } while (0)
#define CP5(d, s) do { d##_0 = s##_0; d##_1 = s##_1; d##_2 = s##_2; d##_3 = s##_3; d##_4 = s##_4; } while (0)
#define ZERO5(p) do { p##_0 = (v2f){0.f,0.f}; p##_1 = (v2f){0.f,0.f}; p##_2 = (v2f){0.f,0.f}; \
    p##_3 = (v2f){0.f,0.f}; p##_4 = (v2f){0.f,0.f}; } while (0)
// packed dot over 5 v2f pairs (v_pk_fma_f32)
#define DOT5(w, x) ((w##_0 * x##_0 + w##_1 * x##_1) + (w##_2 * x##_2 + w##_3 * x##_3) + w##_4 * x##_4)

// uniform 10-vector as named scalars
#define DECLU(u) float u##0, u##1, u##2, u##3, u##4, u##5, u##6, u##7, u##8, u##9
#define ZEROU(u) do { u##0=u##1=u##2=u##3=u##4=u##5=u##6=u##7=u##8=u##9=0.0f; } while (0)
// dot: VGPR weight pairs x uniform vector
#define DOTU(w, u) (fmaf(w##_0.x, u##0, fmaf(w##_0.y, u##1, fmaf(w##_1.x, u##2, fmaf(w##_1.y, u##3, w##_2.x * u##4)))) \
                  + fmaf(w##_2.y, u##5, fmaf(w##_3.x, u##6, fmaf(w##_3.y, u##7, fmaf(w##_4.x, u##8, w##_4.y * u##9)))))

// 10 weight-pair registers (one v2f per input element)
#define DECLW(p) v2f p##0, p##1, p##2, p##3, p##4, p##5, p##6, p##7, p##8, p##9
#define LOADW_PAIR(p, q0, q1) do { \
    p##0 = (v2f){(q0)[0], (q1)[0]}; p##1 = (v2f){(q0)[1], (q1)[1]}; \
    p##2 = (v2f){(q0)[2], (q1)[2]}; p##3 = (v2f){(q0)[3], (q1)[3]}; \
    p##4 = (v2f){(q0)[4], (q1)[4]}; p##5 = (v2f){(q0)[5], (q1)[5]}; \
    p##6 = (v2f){(q0)[6], (q1)[6]}; p##7 = (v2f){(q0)[7], (q1)[7]}; \
    p##8 = (v2f){(q0)[8], (q1)[8]}; p##9 = (v2f){(q0)[9], (q1)[9]}; } while (0)
// acc += Σ_k w_k * splat(s_k)   (10 pk-fma)
#define PKDOT(acc, w, s) do { \
    acc += w##0 * (v2f){s##0, s##0}; acc += w##1 * (v2f){s##1, s##1}; \
    acc += w##2 * (v2f){s##2, s##2}; acc += w##3 * (v2f){s##3, s##3}; \
    acc += w##4 * (v2f){s##4, s##4}; acc += w##5 * (v2f){s##5, s##5}; \
    acc += w##6 * (v2f){s##6, s##6}; acc += w##7 * (v2f){s##7, s##7}; \
    acc += w##8 * (v2f){s##8, s##8}; acc += w##9 * (v2f){s##9, s##9}; } while (0)

#define L1C 508
#define L1P 170
#define L2C 166
#define L2P 56
#define L3C 52
#define L3P 18
#define TT 18

// ---------------------------------------------------------------------------
// K1: per-flow conv1d x3 (+lrelu, +maxpool3 fused) — unchanged from R3/R4.
// ---------------------------------------------------------------------------
__global__ __launch_bounds__(256, 4) void conv_kernel(
    const float* __restrict__ in,
    const float* __restrict__ W1, const float* __restrict__ b1,
    const float* __restrict__ W2, const float* __restrict__ b2,
    const float* __restrict__ W3, const float* __restrict__ b3,
    float* __restrict__ xseq)
{
    __shared__ __align__(16) float xsraw[24 + 1536 + 24];
    __shared__ __align__(16) float y1raw[16 + L1P * 10 + 32];
    __shared__ __align__(16) float y2raw[8 + L2P * 6 + 24];
    float* xs = xsraw + 24;
    float* y1 = y1raw + 16;
    float* y2 = y2raw + 8;

    const int tid = threadIdx.x;
    const int b = blockIdx.x;

    {
        const float4* src = (const float4*)(in + (size_t)b * 1536);
        float4* dst4 = (float4*)xs;
        for (int i = tid; i < 384; i += 256) dst4[i] = src[i];
    }
    __syncthreads();

    // ---- conv1 (3->10, k5) + lrelu + pool3 -> y1[170][10] ----
    {
        const int co = tid % 10;
        const int ob = tid / 10;
        if (tid < 250) {
            float w[15];
            #pragma unroll
            for (int q = 0; q < 15; ++q) w[q] = W1[co * 15 + q];
            const float bias = b1[co];
            const int o0 = ob * 7;
            int sb = 3 * o0 - 1;
            float win[21];
            #pragma unroll
            for (int q = 0; q < 21; ++q) win[q] = xs[3 * sb + q];
            #pragma unroll
            for (int r = 0; r < 7; ++r) {
                const int o = o0 + r;
                if (o < L1P) {
                    float a0 = bias, a1 = bias, a2 = bias;
                    #pragma unroll
                    for (int p = 0; p < 3; ++p) {
                        #pragma unroll
                        for (int k = 0; k < 5; ++k) {
                            const float wv = w[p * 5 + k];
                            a0 = fmaf(wv, win[3 * k + p], a0);
                            a1 = fmaf(wv, win[3 * (k + 1) + p], a1);
                            a2 = fmaf(wv, win[3 * (k + 2) + p], a2);
                        }
                    }
                    float best = -3.0e38f;
                    if (sb >= 0)        best = fmaxf(best, lrelu(a0));
                    best = fmaxf(best, lrelu(a1));
                    if (sb + 2 < L1C)   best = fmaxf(best, lrelu(a2));
                    y1[o * 10 + co] = best;
                }
                if (r < 6 && o + 1 < L1P) {
                    #pragma unroll
                    for (int q = 0; q < 12; ++q) win[q] = win[q + 9];
                    #pragma unroll
                    for (int q = 0; q < 9; ++q) win[12 + q] = xs[3 * sb + 21 + q];
                    sb += 3;
                }
            }
        }
    }
    __syncthreads();

    // ---- conv2 (10->5, k5) + lrelu + pool3 -> y2[56][6-stride] ----
    {
        const int co = tid % 5;
        const int ob = tid / 5;
        v2f wv2[25];
        #pragma unroll
        for (int c2 = 0; c2 < 5; ++c2)
            #pragma unroll
            for (int k = 0; k < 5; ++k)
                wv2[c2 * 5 + k] = (v2f){W2[co * 50 + (2 * c2) * 5 + k],
                                        W2[co * 50 + (2 * c2 + 1) * 5 + k]};
        const float bias = b2[co];
        if (tid < 255) {
            for (int r = 0; r < 2; ++r) {
                const int o = ob + 51 * r;
                if (o < L2P) {
                    const int t0 = 3 * o - 1;
                    v2f v0 = {0.f, 0.f}, v1 = {0.f, 0.f}, v2 = {0.f, 0.f};
                    #pragma unroll
                    for (int m = 0; m < 7; ++m) {
                        v2f rows5[5];
                        const v2f* pr = (const v2f*)(y1 + (t0 + m) * 10);
                        #pragma unroll
                        for (int c2 = 0; c2 < 5; ++c2) rows5[c2] = pr[c2];
                        #pragma unroll
                        for (int c2 = 0; c2 < 5; ++c2) {
                            if (m < 5)            v0 += wv2[c2 * 5 + m] * rows5[c2];
                            if (m >= 1 && m <= 5) v1 += wv2[c2 * 5 + m - 1] * rows5[c2];
                            if (m >= 2)           v2 += wv2[c2 * 5 + m - 2] * rows5[c2];
                        }
                    }
                    const float a0 = bias + v0.x + v0.y;
                    const float a1 = bias + v1.x + v1.y;
                    const float a2 = bias + v2.x + v2.y;
                    float best = -3.0e38f;
                    if (t0 >= 0)        best = fmaxf(best, lrelu(a0));
                    best = fmaxf(best, lrelu(a1));
                    if (t0 + 2 < L2C)   best = fmaxf(best, lrelu(a2));
                    y2[o * 6 + co] = best;
                }
            }
        }
    }
    __syncthreads();

    // ---- conv3 (5->10, k5) + lrelu + pool3 -> xseq ----
    {
        const int co = tid % 10;
        const int o = tid / 10;
        if (o < L3P) {
            v2f wv3[10];
            float ws3[5];
            #pragma unroll
            for (int c2 = 0; c2 < 2; ++c2)
                #pragma unroll
                for (int k = 0; k < 5; ++k)
                    wv3[c2 * 5 + k] = (v2f){W3[co * 25 + (2 * c2) * 5 + k],
                                            W3[co * 25 + (2 * c2 + 1) * 5 + k]};
            #pragma unroll
            for (int k = 0; k < 5; ++k) ws3[k] = W3[co * 25 + 20 + k];
            const float bias = b3[co];
            const int t0 = 3 * o - 1;
            v2f v0 = {0.f, 0.f}, v1 = {0.f, 0.f}, v2 = {0.f, 0.f};
            float s0 = 0.f, s1 = 0.f, s2 = 0.f;
            #pragma unroll
            for (int m = 0; m < 7; ++m) {
                const float* base = y2 + (t0 + m) * 6;
                v2f ra0 = ((const v2f*)base)[0];
                v2f ra1 = ((const v2f*)base)[1];
                float rcm = base[4];
                if (m < 5) {
                    v0 += wv3[m] * ra0; v0 += wv3[5 + m] * ra1;
                    s0 = fmaf(ws3[m], rcm, s0);
                }
                if (m >= 1 && m <= 5) {
                    v1 += wv3[m - 1] * ra0; v1 += wv3[5 + m - 1] * ra1;
                    s1 = fmaf(ws3[m - 1], rcm, s1);
                }
                if (m >= 2) {
                    v2 += wv3[m - 2] * ra0; v2 += wv3[5 + m - 2] * ra1;
                    s2 = fmaf(ws3[m - 2], rcm, s2);
                }
            }
            const float a0 = bias + s0 + v0.x + v0.y;
            const float a1 = bias + s1 + v1.x + v1.y;
            const float a2 = bias + s2 + v2.x + v2.y;
            float best = -3.0e38f;
            if (t0 >= 0)        best = fmaxf(best, lrelu(a0));
            best = fmaxf(best, lrelu(a1));
            if (t0 + 2 < L3C)   best = fmaxf(best, lrelu(a2));
            xseq[(size_t)b * 180 + o * 10 + co] = best;
        }
    }
}

// ---------------------------------------------------------------------------
// K2: flow LSTM — unchanged from R4.
// ---------------------------------------------------------------------------
__global__ __launch_bounds__(256, 2) void flow_lstm_kernel(
    const float* __restrict__ xseq,
    const float* __restrict__ fWih, const float* __restrict__ fWhh,
    const float* __restrict__ fb,
    float* __restrict__ fv)
{
    __shared__ __align__(16) float sbuf[3][16 * 18 * 10];
    const int tid = threadIdx.x;
    const int blk = blockIdx.x;

    {
        const float* src = xseq + (size_t)blk * 2880;
        for (int i = tid; i < 2880; i += 256) sbuf[0][i] = src[i];
    }
    __syncthreads();

    const int el = tid >> 4;
    const int j = tid & 15;
    const int jj = (j < 10) ? j : 0;
    const int base = el * 180;
    const int lane = tid & 63;
    const int gbase = lane & 48;

    float fv_acc = 0.0f;

    for (int l = 0; l < 3; ++l) {
        const float* Wi = fWih + l * 400;
        const float* Wh = fWhh + l * 400;
        const float* bb = fb + l * 40;
        DECL5(wii); DECL5(wif); DECL5(wig); DECL5(wio);
        DECL5(whi); DECL5(whf); DECL5(whg); DECL5(who);
        LOAD5(wii, Wi + jj * 10);
        LOAD5(wif, Wi + (10 + jj) * 10);
        LOAD5(wig, Wi + (20 + jj) * 10);
        LOAD5(wio, Wi + (30 + jj) * 10);
        LOAD5(whi, Wh + jj * 10);
        LOAD5(whf, Wh + (10 + jj) * 10);
        LOAD5(whg, Wh + (20 + jj) * 10);
        LOAD5(who, Wh + (30 + jj) * 10);
        const float bi = bb[jj], bf = bb[10 + jj], bg = bb[20 + jj], bo = bb[30 + jj];

        const float* inb = sbuf[l];
        float* outb = sbuf[(l + 1) % 3];
        float c = 0.0f, hj = 0.0f;
        DECL5(hv); ZERO5(hv);
        DECL5(xc); DECL5(xn);
        LOAD5(xc, inb + base);

        for (int t = 0; t < TT; ++t) {
            if (t + 1 < TT) LOAD5(xn, inb + base + (t + 1) * 10);
            v2f ti_ = DOT5(wii, xc) + DOT5(whi, hv);
            v2f tf_ = DOT5(wif, xc) + DOT5(whf, hv);
            v2f tg_ = DOT5(wig, xc) + DOT5(whg, hv);
            v2f to_ = DOT5(wio, xc) + DOT5(who, hv);
            const float ai = sigmoid_f(bi + ti_.x + ti_.y);
            const float af = sigmoid_f(bf + tf_.x + tf_.y);
            const float ag = tanh_f(bg + tg_.x + tg_.y);
            const float ao = sigmoid_f(bo + to_.x + to_.y);
            c = af * c + ai * ag;
            hj = ao * tanh_f(c);
            if (j < 10) outb[base + t * 10 + j] = hj;
            hv_0 = (v2f){__shfl(hj, gbase + 0), __shfl(hj, gbase + 1)};
            hv_1 = (v2f){__shfl(hj, gbase + 2), __shfl(hj, gbase + 3)};
            hv_2 = (v2f){__shfl(hj, gbase + 4), __shfl(hj, gbase + 5)};
            hv_3 = (v2f){__shfl(hj, gbase + 6), __shfl(hj, gbase + 7)};
            hv_4 = (v2f){__shfl(hj, gbase + 8), __shfl(hj, gbase + 9)};
            CP5(xc, xn);
        }
        if (l >= 1) fv_acc += hj;
        __asm__ __volatile__("" ::: "memory");
    }
    if (j < 10) fv[(size_t)(blk * 16 + el) * 10 + j] = fv_acc;
}

// ---------------------------------------------------------------------------
// K3: trace LSTM (3 layers, T=64, H=10), one wave per trace row, + fused MLP.
// DS-FREE recurrence: lanes 0-9/10-19/20-29 own layer 0/1/2; each lane
// computes ALL FOUR gates of its hidden unit as two packed (v_pk_fma_f32)
// accumulators -> cell update is lane-local, NO shfl gather. Cross-lane is
// 30 constant-lane v_readlane into uniform u0/u1/u2; layer inputs/hiddens
// selected per-lane from those via cndmask. Single uniform loop tau=0..65
// with per-lane activity window g <= tau <= 63+g gating commits.
// ---------------------------------------------------------------------------
__global__ __launch_bounds__(64, 1) void trace_mlp_kernel(
    const float* __restrict__ fv,
    const float* __restrict__ tWih, const float* __restrict__ tWhh,
    const float* __restrict__ tb,
    const float* __restrict__ L1W, const float* __restrict__ L1b,
    const float* __restrict__ L2W, const float* __restrict__ L2b,
    const float* __restrict__ L3W, const float* __restrict__ L3b,
    const float* __restrict__ L4W, const float* __restrict__ L4b,
    float* __restrict__ out)
{
    __shared__ __align__(16) float xrow[640];
    __shared__ __align__(16) float m1[128];
    __shared__ __align__(16) float m2b[256];
    __shared__ __align__(16) float m3[64];

    const int lane = threadIdx.x;
    const int ti = blockIdx.x;

    {
        const float4* src = (const float4*)(fv + (size_t)ti * 640);
        float4* dst = (float4*)xrow;
        for (int i = lane; i < 160; i += 64) dst[i] = src[i];
    }
    __asm__ __volatile__("" ::: "memory");   // same-wave DS ordering

    const int g = (lane < 30) ? (lane / 10) : 2;   // layer this lane serves
    const int j = lane % 10;                        // hidden unit

    // weight pairs for this lane's layer/unit: A=(i,f), B=(g,o)
    const float* WiL = tWih + g * 400;
    const float* WhL = tWhh + g * 400;
    const float* bL  = tb + g * 40;
    DECLW(wxA); DECLW(wxB); DECLW(whA); DECLW(whB);
    LOADW_PAIR(wxA, WiL + j * 10,        WiL + (10 + j) * 10);
    LOADW_PAIR(wxB, WiL + (20 + j) * 10, WiL + (30 + j) * 10);
    LOADW_PAIR(whA, WhL + j * 10,        WhL + (10 + j) * 10);
    LOADW_PAIR(whB, WhL + (20 + j) * 10, WhL + (30 + j) * 10);
    const v2f bA = (v2f){bL[j], bL[10 + j]};
    const v2f bB = (v2f){bL[20 + j], bL[30 + j]};

    DECLU(u0); DECLU(u1); DECLU(u2);    // uniform h state (readlane-produced)
    ZEROU(u0); ZEROU(u1); ZEROU(u2);
    float c = 0.0f, h = 0.0f;
    const int tlo = g, thi = 63 + g;    // activity window for this lane's layer
    const bool g0 = (g == 0), g1 = (g == 1);

    DECL5(xc); DECL5(xn);
    LOAD5(xc, xrow);

    for (int tau = 0; tau < 66; ++tau) {
        const int tn = (tau + 1 < 64) ? (tau + 1) : 63;
        LOAD5(xn, xrow + tn * 10);      // prefetch; consumed next tick

        // per-lane input vector: layer0 <- x(t), layer1 <- u0, layer2 <- u1
        const float in0 = g0 ? xc_0.x : (g1 ? u00 : u10);
        const float in1 = g0 ? xc_0.y : (g1 ? u01 : u11);
        const float in2 = g0 ? xc_1.x : (g1 ? u02 : u12);
        const float in3 = g0 ? xc_1.y : (g1 ? u03 : u13);
        const float in4 = g0 ? xc_2.x : (g1 ? u04 : u14);
        const float in5 = g0 ? xc_2.y : (g1 ? u05 : u15);
        const float in6 = g0 ? xc_3.x : (g1 ? u06 : u16);
        const float in7 = g0 ? xc_3.y : (g1 ? u07 : u17);
        const float in8 = g0 ? xc_4.x : (g1 ? u08 : u18);
        const float in9 = g0 ? xc_4.y : (g1 ? u09 : u19);
        // per-lane hidden vector: own layer's h
        const float hd0 = g0 ? u00 : (g1 ? u10 : u20);
        const float hd1 = g0 ? u01 : (g1 ? u11 : u21);
        const float hd2 = g0 ? u02 : (g1 ? u12 : u22);
        const float hd3 = g0 ? u03 : (g1 ? u13 : u23);
        const float hd4 = g0 ? u04 : (g1 ? u14 : u24);
        const float hd5 = g0 ? u05 : (g1 ? u15 : u25);
        const float hd6 = g0 ? u06 : (g1 ? u16 : u26);
        const float hd7 = g0 ? u07 : (g1 ? u17 : u27);
        const float hd8 = g0 ? u08 : (g1 ? u18 : u28);
        const float hd9 = g0 ? u09 : (g1 ? u19 : u29);

        v2f gA = bA, gB = bB;
        PKDOT(gA, wxA, in); PKDOT(gB, wxB, in);
        PKDOT(gA, whA, hd); PKDOT(gB, whB, hd);

        const float ai = sigmoid_f(gA.x);
        const float af = sigmoid_f(gA.y);
        const float ag = tanh_f(gB.x);
        const float ao = sigmoid_f(gB.y);
        const float cn = af * c + ai * ag;
        const float hn = ao * tanh_f(cn);
        const bool act = (tau >= tlo) && (tau <= thi);
        c = act ? cn : c;
        h = act ? hn : h;

        u00 = readlane_f(h, 0); u01 = readlane_f(h, 1); u02 = readlane_f(h, 2);
        u03 = readlane_f(h, 3); u04 = readlane_f(h, 4); u05 = readlane_f(h, 5);
        u06 = readlane_f(h, 6); u07 = readlane_f(h, 7); u08 = readlane_f(h, 8);
        u09 = readlane_f(h, 9);
        u10 = readlane_f(h, 10); u11 = readlane_f(h, 11); u12 = readlane_f(h, 12);
        u13 = readlane_f(h, 13); u14 = readlane_f(h, 14); u15 = readlane_f(h, 15);
        u16 = readlane_f(h, 16); u17 = readlane_f(h, 17); u18 = readlane_f(h, 18);
        u19 = readlane_f(h, 19);
        u20 = readlane_f(h, 20); u21 = readlane_f(h, 21); u22 = readlane_f(h, 22);
        u23 = readlane_f(h, 23); u24 = readlane_f(h, 24); u25 = readlane_f(h, 25);
        u26 = readlane_f(h, 26); u27 = readlane_f(h, 27); u28 = readlane_f(h, 28);
        u29 = readlane_f(h, 29);

        CP5(xc, xn);
    }

    // tv = h_n(layer2) + h_n(layer1): uniform
    DECLU(tv);
    tv0 = u10 + u20; tv1 = u11 + u21; tv2 = u12 + u22; tv3 = u13 + u23;
    tv4 = u14 + u24; tv5 = u15 + u25; tv6 = u16 + u26; tv7 = u17 + u27;
    tv8 = u18 + u28; tv9 = u19 + u29;

    // ---- fused per-row MLP: 10 ->128 ->256 ->64 ->7 ----
    {
        DECL5(w1a); DECL5(w1b);
        LOAD5(w1a, L1W + lane * 10);
        LOAD5(w1b, L1W + (lane + 64) * 10);
        float a0 = L1b[lane] + DOTU(w1a, tv);
        float a1 = L1b[lane + 64] + DOTU(w1b, tv);
        m1[lane] = lrelu(a0);
        m1[lane + 64] = lrelu(a1);
    }
    __asm__ __volatile__("" ::: "memory");
    {
        float acc0 = L2b[lane];
        float acc1 = L2b[lane + 64];
        float acc2 = L2b[lane + 128];
        float acc3 = L2b[lane + 192];
        for (int k = 0; k < 128; k += 4) {
            float4 hv = *(const float4*)(m1 + k);
            float4 w0 = *(const float4*)(L2W + (size_t)lane * 128 + k);
            float4 w1 = *(const float4*)(L2W + (size_t)(lane + 64) * 128 + k);
            float4 w2 = *(const float4*)(L2W + (size_t)(lane + 128) * 128 + k);
            float4 w3 = *(const float4*)(L2W + (size_t)(lane + 192) * 128 + k);
            acc0 = fmaf(w0.x, hv.x, acc0); acc0 = fmaf(w0.y, hv.y, acc0);
            acc0 = fmaf(w0.z, hv.z, acc0); acc0 = fmaf(w0.w, hv.w, acc0);
            acc1 = fmaf(w1.x, hv.x, acc1); acc1 = fmaf(w1.y, hv.y, acc1);
            acc1 = fmaf(w1.z, hv.z, acc1); acc1 = fmaf(w1.w, hv.w, acc1);
            acc2 = fmaf(w2.x, hv.x, acc2); acc2 = fmaf(w2.y, hv.y, acc2);
            acc2 = fmaf(w2.z, hv.z, acc2); acc2 = fmaf(w2.w, hv.w, acc2);
            acc3 = fmaf(w3.x, hv.x, acc3); acc3 = fmaf(w3.y, hv.y, acc3);
            acc3 = fmaf(w3.z, hv.z, acc3); acc3 = fmaf(w3.w, hv.w, acc3);
        }
        m2b[lane] = lrelu(acc0);
        m2b[lane + 64] = lrelu(acc1);
        m2b[lane + 128] = lrelu(acc2);
        m2b[lane + 192] = lrelu(acc3);
    }
    __asm__ __volatile__("" ::: "memory");
    {
        float acc = L3b[lane];
        for (int k = 0; k < 256; k += 4) {
            float4 hv = *(const float4*)(m2b + k);
            float4 wv = *(const float4*)(L3W + (size_t)lane * 256 + k);
            acc = fmaf(wv.x, hv.x, acc);
            acc = fmaf(wv.y, hv.y, acc);
            acc = fmaf(wv.z, hv.z, acc);
            acc = fmaf(wv.w, hv.w, acc);
        }
        m3[lane] = lrelu(acc);
    }
    __asm__ __volatile__("" ::: "memory");
    if (lane < 7) {
        float acc = L4b[lane];
        #pragma unroll
        for (int k = 0; k < 64; k += 4) {
            float4 hv = *(const float4*)(m3 + k);
            float4 wv = *(const float4*)(L4W + lane * 64 + k);
            acc = fmaf(wv.x, hv.x, acc);
            acc = fmaf(wv.y, hv.y, acc);
            acc = fmaf(wv.z, hv.z, acc);
            acc = fmaf(wv.w, hv.w, acc);
        }
        out[ti * 7 + lane] = acc;
    }
}

// ---------------------------------------------------------------------------
extern "C" void kernel_launch(void* const* d_in, const int* in_sizes, int n_in,
                              void* d_out, int out_size, void* d_ws, size_t ws_size,
                              hipStream_t stream)
{
    const float* data_in = (const float*)d_in[0];
    const float* W1 = (const float*)d_in[1];
    const float* b1 = (const float*)d_in[2];
    const float* W2 = (const float*)d_in[3];
    const float* b2 = (const float*)d_in[4];
    const float* W3 = (const float*)d_in[5];
    const float* b3 = (const float*)d_in[6];
    const float* fWih = (const float*)d_in[7];
    const float* fWhh = (const float*)d_in[8];
    const float* fb = (const float*)d_in[9];
    const float* tWih = (const float*)d_in[10];
    const float* tWhh = (const float*)d_in[11];
    const float* tb = (const float*)d_in[12];
    const float* L1W = (const float*)d_in[13];
    const float* L1b = (const float*)d_in[14];
    const float* L2W = (const float*)d_in[15];
    const float* L2b = (const float*)d_in[16];
    const float* L3W = (const float*)d_in[17];
    const float* L3b = (const float*)d_in[18];
    const float* L4W = (const float*)d_in[19];
    const float* L4b = (const float*)d_in[20];

    float* xseq = (float*)d_ws;            // 4096*180 floats
    float* fv = xseq + 4096 * 180;         // 4096*10 floats
    float* outp = (float*)d_out;           // 64*7 floats

    conv_kernel<<<4096, 256, 0, stream>>>(data_in, W1, b1, W2, b2, W3, b3, xseq);
    flow_lstm_kernel<<<256, 256, 0, stream>>>(xseq, fWih, fWhh, fb, fv);
    trace_mlp_kernel<<<64, 64, 0, stream>>>(fv, tWih, tWhh, tb,
                                            L1W, L1b, L2W, L2b, L3W, L3b,
                                            L4W, L4b, outp);
}

// Round 6
// 200.284 us; speedup vs baseline: 1.0045x; 1.0045x over previous
//
#include <hip/hip_runtime.h>
#include <math.h>

#define LEAK 0.01f

typedef float v2f __attribute__((ext_vector_type(2)));

// opaque pass-through: result of asm cannot be rematerialized by LLVM,
// forcing the value to stay register-resident across the loop.
#define PIN(x) asm("" : "+v"(x))

__device__ __forceinline__ float lrelu(float x) { return fmaxf(x, LEAK * x); }
__device__ __forceinline__ float fast_rcp(float x) { return __builtin_amdgcn_rcpf(x); }
__device__ __forceinline__ float sigmoid_f(float x) {
    return fast_rcp(1.0f + exp2f(-1.44269504f * x));
}
__device__ __forceinline__ float tanh_f(float x) {
    return 2.0f * fast_rcp(1.0f + exp2f(-2.88539008f * x)) - 1.0f;
}
__device__ __forceinline__ float readlane_f(float v, int l) {
    return __int_as_float(__builtin_amdgcn_readlane(__float_as_int(v), l));
}

// ---- named-scalar helpers (NO arrays: guarantees SROA/register residency) ----
#define DECL5(p) v2f p##_0, p##_1, p##_2, p##_3, p##_4
#define LOAD5(p, src) do { const v2f* _s5 = (const v2f*)(src); \
    p##_0 = _s5[0]; p##_1 = _s5[1]; p##_2 = _s5[2]; p##_3 = _s5[3]; p##_4 = _s5[4]; } while (0)
#define CP5(d, s) do { d##_0 = s##_0; d##_1 = s##_1; d##_2 = s##_2; d##_3 = s##_3; d##_4 = s##_4; } while (0)
#define ZERO5(p) do { p##_0 = (v2f){0.f,0.f}; p##_1 = (v2f){0.f,0.f}; p##_2 = (v2f){0.f,0.f}; \
    p##_3 = (v2f){0.f,0.f}; p##_4 = (v2f){0.f,0.f}; } while (0)
// packed dot over 5 v2f pairs (v_pk_fma_f32)
#define DOT5(w, x) ((w##_0 * x##_0 + w##_1 * x##_1) + (w##_2 * x##_2 + w##_3 * x##_3) + w##_4 * x##_4)

// uniform 10-vector as named scalars
#define DECLU(u) float u##0, u##1, u##2, u##3, u##4, u##5, u##6, u##7, u##8, u##9
#define ZEROU(u) do { u##0=u##1=u##2=u##3=u##4=u##5=u##6=u##7=u##8=u##9=0.0f; } while (0)
// dot: VGPR weight pairs x uniform vector
#define DOTU(w, u) (fmaf(w##_0.x, u##0, fmaf(w##_0.y, u##1, fmaf(w##_1.x, u##2, fmaf(w##_1.y, u##3, w##_2.x * u##4)))) \
                  + fmaf(w##_2.y, u##5, fmaf(w##_3.x, u##6, fmaf(w##_3.y, u##7, fmaf(w##_4.x, u##8, w##_4.y * u##9)))))

// 10 weight-pair registers (one v2f per input element)
#define DECLW(p) v2f p##0, p##1, p##2, p##3, p##4, p##5, p##6, p##7, p##8, p##9
#define LOADW_PAIR(p, q0, q1) do { \
    p##0 = (v2f){(q0)[0], (q1)[0]}; p##1 = (v2f){(q0)[1], (q1)[1]}; \
    p##2 = (v2f){(q0)[2], (q1)[2]}; p##3 = (v2f){(q0)[3], (q1)[3]}; \
    p##4 = (v2f){(q0)[4], (q1)[4]}; p##5 = (v2f){(q0)[5], (q1)[5]}; \
    p##6 = (v2f){(q0)[6], (q1)[6]}; p##7 = (v2f){(q0)[7], (q1)[7]}; \
    p##8 = (v2f){(q0)[8], (q1)[8]}; p##9 = (v2f){(q0)[9], (q1)[9]}; } while (0)
#define PINW(p) do { PIN(p##0); PIN(p##1); PIN(p##2); PIN(p##3); PIN(p##4); \
    PIN(p##5); PIN(p##6); PIN(p##7); PIN(p##8); PIN(p##9); } while (0)
// acc += Σ_k w_k * splat(s_k)   (10 pk-fma)
#define PKDOT(acc, w, s) do { \
    acc += w##0 * (v2f){s##0, s##0}; acc += w##1 * (v2f){s##1, s##1}; \
    acc += w##2 * (v2f){s##2, s##2}; acc += w##3 * (v2f){s##3, s##3}; \
    acc += w##4 * (v2f){s##4, s##4}; acc += w##5 * (v2f){s##5, s##5}; \
    acc += w##6 * (v2f){s##6, s##6}; acc += w##7 * (v2f){s##7, s##7}; \
    acc += w##8 * (v2f){s##8, s##8}; acc += w##9 * (v2f){s##9, s##9}; } while (0)

#define L1C 508
#define L1P 170
#define L2C 166
#define L2P 56
#define L3C 52
#define L3P 18
#define TT 18

// ---------------------------------------------------------------------------
// K1: per-flow conv1d x3 (+lrelu, +maxpool3 fused) — unchanged.
// ---------------------------------------------------------------------------
__global__ __launch_bounds__(256, 4) void conv_kernel(
    const float* __restrict__ in,
    const float* __restrict__ W1, const float* __restrict__ b1,
    const float* __restrict__ W2, const float* __restrict__ b2,
    const float* __restrict__ W3, const float* __restrict__ b3,
    float* __restrict__ xseq)
{
    __shared__ __align__(16) float xsraw[24 + 1536 + 24];
    __shared__ __align__(16) float y1raw[16 + L1P * 10 + 32];
    __shared__ __align__(16) float y2raw[8 + L2P * 6 + 24];
    float* xs = xsraw + 24;
    float* y1 = y1raw + 16;
    float* y2 = y2raw + 8;

    const int tid = threadIdx.x;
    const int b = blockIdx.x;

    {
        const float4* src = (const float4*)(in + (size_t)b * 1536);
        float4* dst4 = (float4*)xs;
        for (int i = tid; i < 384; i += 256) dst4[i] = src[i];
    }
    __syncthreads();

    // ---- conv1 (3->10, k5) + lrelu + pool3 -> y1[170][10] ----
    {
        const int co = tid % 10;
        const int ob = tid / 10;
        if (tid < 250) {
            float w[15];
            #pragma unroll
            for (int q = 0; q < 15; ++q) w[q] = W1[co * 15 + q];
            const float bias = b1[co];
            const int o0 = ob * 7;
            int sb = 3 * o0 - 1;
            float win[21];
            #pragma unroll
            for (int q = 0; q < 21; ++q) win[q] = xs[3 * sb + q];
            #pragma unroll
            for (int r = 0; r < 7; ++r) {
                const int o = o0 + r;
                if (o < L1P) {
                    float a0 = bias, a1 = bias, a2 = bias;
                    #pragma unroll
                    for (int p = 0; p < 3; ++p) {
                        #pragma unroll
                        for (int k = 0; k < 5; ++k) {
                            const float wv = w[p * 5 + k];
                            a0 = fmaf(wv, win[3 * k + p], a0);
                            a1 = fmaf(wv, win[3 * (k + 1) + p], a1);
                            a2 = fmaf(wv, win[3 * (k + 2) + p], a2);
                        }
                    }
                    float best = -3.0e38f;
                    if (sb >= 0)        best = fmaxf(best, lrelu(a0));
                    best = fmaxf(best, lrelu(a1));
                    if (sb + 2 < L1C)   best = fmaxf(best, lrelu(a2));
                    y1[o * 10 + co] = best;
                }
                if (r < 6 && o + 1 < L1P) {
                    #pragma unroll
                    for (int q = 0; q < 12; ++q) win[q] = win[q + 9];
                    #pragma unroll
                    for (int q = 0; q < 9; ++q) win[12 + q] = xs[3 * sb + 21 + q];
                    sb += 3;
                }
            }
        }
    }
    __syncthreads();

    // ---- conv2 (10->5, k5) + lrelu + pool3 -> y2[56][6-stride] ----
    {
        const int co = tid % 5;
        const int ob = tid / 5;
        v2f wv2[25];
        #pragma unroll
        for (int c2 = 0; c2 < 5; ++c2)
            #pragma unroll
            for (int k = 0; k < 5; ++k)
                wv2[c2 * 5 + k] = (v2f){W2[co * 50 + (2 * c2) * 5 + k],
                                        W2[co * 50 + (2 * c2 + 1) * 5 + k]};
        const float bias = b2[co];
        if (tid < 255) {
            for (int r = 0; r < 2; ++r) {
                const int o = ob + 51 * r;
                if (o < L2P) {
                    const int t0 = 3 * o - 1;
                    v2f v0 = {0.f, 0.f}, v1 = {0.f, 0.f}, v2 = {0.f, 0.f};
                    #pragma unroll
                    for (int m = 0; m < 7; ++m) {
                        v2f rows5[5];
                        const v2f* pr = (const v2f*)(y1 + (t0 + m) * 10);
                        #pragma unroll
                        for (int c2 = 0; c2 < 5; ++c2) rows5[c2] = pr[c2];
                        #pragma unroll
                        for (int c2 = 0; c2 < 5; ++c2) {
                            if (m < 5)            v0 += wv2[c2 * 5 + m] * rows5[c2];
                            if (m >= 1 && m <= 5) v1 += wv2[c2 * 5 + m - 1] * rows5[c2];
                            if (m >= 2)           v2 += wv2[c2 * 5 + m - 2] * rows5[c2];
                        }
                    }
                    const float a0 = bias + v0.x + v0.y;
                    const float a1 = bias + v1.x + v1.y;
                    const float a2 = bias + v2.x + v2.y;
                    float best = -3.0e38f;
                    if (t0 >= 0)        best = fmaxf(best, lrelu(a0));
                    best = fmaxf(best, lrelu(a1));
                    if (t0 + 2 < L2C)   best = fmaxf(best, lrelu(a2));
                    y2[o * 6 + co] = best;
                }
            }
        }
    }
    __syncthreads();

    // ---- conv3 (5->10, k5) + lrelu + pool3 -> xseq ----
    {
        const int co = tid % 10;
        const int o = tid / 10;
        if (o < L3P) {
            v2f wv3[10];
            float ws3[5];
            #pragma unroll
            for (int c2 = 0; c2 < 2; ++c2)
                #pragma unroll
                for (int k = 0; k < 5; ++k)
                    wv3[c2 * 5 + k] = (v2f){W3[co * 25 + (2 * c2) * 5 + k],
                                            W3[co * 25 + (2 * c2 + 1) * 5 + k]};
            #pragma unroll
            for (int k = 0; k < 5; ++k) ws3[k] = W3[co * 25 + 20 + k];
            const float bias = b3[co];
            const int t0 = 3 * o - 1;
            v2f v0 = {0.f, 0.f}, v1 = {0.f, 0.f}, v2 = {0.f, 0.f};
            float s0 = 0.f, s1 = 0.f, s2 = 0.f;
            #pragma unroll
            for (int m = 0; m < 7; ++m) {
                const float* base = y2 + (t0 + m) * 6;
                v2f ra0 = ((const v2f*)base)[0];
                v2f ra1 = ((const v2f*)base)[1];
                float rcm = base[4];
                if (m < 5) {
                    v0 += wv3[m] * ra0; v0 += wv3[5 + m] * ra1;
                    s0 = fmaf(ws3[m], rcm, s0);
                }
                if (m >= 1 && m <= 5) {
                    v1 += wv3[m - 1] * ra0; v1 += wv3[5 + m - 1] * ra1;
                    s1 = fmaf(ws3[m - 1], rcm, s1);
                }
                if (m >= 2) {
                    v2 += wv3[m - 2] * ra0; v2 += wv3[5 + m - 2] * ra1;
                    s2 = fmaf(ws3[m - 2], rcm, s2);
                }
            }
            const float a0 = bias + s0 + v0.x + v0.y;
            const float a1 = bias + s1 + v1.x + v1.y;
            const float a2 = bias + s2 + v2.x + v2.y;
            float best = -3.0e38f;
            if (t0 >= 0)        best = fmaxf(best, lrelu(a0));
            best = fmaxf(best, lrelu(a1));
            if (t0 + 2 < L3C)   best = fmaxf(best, lrelu(a2));
            xseq[(size_t)b * 180 + o * 10 + co] = best;
        }
    }
}

// ---------------------------------------------------------------------------
// K2: flow LSTM — unchanged.
// ---------------------------------------------------------------------------
__global__ __launch_bounds__(256, 2) void flow_lstm_kernel(
    const float* __restrict__ xseq,
    const float* __restrict__ fWih, const float* __restrict__ fWhh,
    const float* __restrict__ fb,
    float* __restrict__ fv)
{
    __shared__ __align__(16) float sbuf[3][16 * 18 * 10];
    const int tid = threadIdx.x;
    const int blk = blockIdx.x;

    {
        const float* src = xseq + (size_t)blk * 2880;
        for (int i = tid; i < 2880; i += 256) sbuf[0][i] = src[i];
    }
    __syncthreads();

    const int el = tid >> 4;
    const int j = tid & 15;
    const int jj = (j < 10) ? j : 0;
    const int base = el * 180;
    const int lane = tid & 63;
    const int gbase = lane & 48;

    float fv_acc = 0.0f;

    for (int l = 0; l < 3; ++l) {
        const float* Wi = fWih + l * 400;
        const float* Wh = fWhh + l * 400;
        const float* bb = fb + l * 40;
        DECL5(wii); DECL5(wif); DECL5(wig); DECL5(wio);
        DECL5(whi); DECL5(whf); DECL5(whg); DECL5(who);
        LOAD5(wii, Wi + jj * 10);
        LOAD5(wif, Wi + (10 + jj) * 10);
        LOAD5(wig, Wi + (20 + jj) * 10);
        LOAD5(wio, Wi + (30 + jj) * 10);
        LOAD5(whi, Wh + jj * 10);
        LOAD5(whf, Wh + (10 + jj) * 10);
        LOAD5(whg, Wh + (20 + jj) * 10);
        LOAD5(who, Wh + (30 + jj) * 10);
        const float bi = bb[jj], bf = bb[10 + jj], bg = bb[20 + jj], bo = bb[30 + jj];

        const float* inb = sbuf[l];
        float* outb = sbuf[(l + 1) % 3];
        float c = 0.0f, hj = 0.0f;
        DECL5(hv); ZERO5(hv);
        DECL5(xc); DECL5(xn);
        LOAD5(xc, inb + base);

        for (int t = 0; t < TT; ++t) {
            if (t + 1 < TT) LOAD5(xn, inb + base + (t + 1) * 10);
            v2f ti_ = DOT5(wii, xc) + DOT5(whi, hv);
            v2f tf_ = DOT5(wif, xc) + DOT5(whf, hv);
            v2f tg_ = DOT5(wig, xc) + DOT5(whg, hv);
            v2f to_ = DOT5(wio, xc) + DOT5(who, hv);
            const float ai = sigmoid_f(bi + ti_.x + ti_.y);
            const float af = sigmoid_f(bf + tf_.x + tf_.y);
            const float ag = tanh_f(bg + tg_.x + tg_.y);
            const float ao = sigmoid_f(bo + to_.x + to_.y);
            c = af * c + ai * ag;
            hj = ao * tanh_f(c);
            if (j < 10) outb[base + t * 10 + j] = hj;
            hv_0 = (v2f){__shfl(hj, gbase + 0), __shfl(hj, gbase + 1)};
            hv_1 = (v2f){__shfl(hj, gbase + 2), __shfl(hj, gbase + 3)};
            hv_2 = (v2f){__shfl(hj, gbase + 4), __shfl(hj, gbase + 5)};
            hv_3 = (v2f){__shfl(hj, gbase + 6), __shfl(hj, gbase + 7)};
            hv_4 = (v2f){__shfl(hj, gbase + 8), __shfl(hj, gbase + 9)};
            CP5(xc, xn);
        }
        if (l >= 1) fv_acc += hj;
        __asm__ __volatile__("" ::: "memory");
    }
    if (j < 10) fv[(size_t)(blk * 16 + el) * 10 + j] = fv_acc;
}

// ---------------------------------------------------------------------------
// K3: trace LSTM (3 layers, T=64, H=10), one wave per trace row, + fused MLP.
// DS-free recurrence (R5) + PINNED weights: every weight v2f is routed
// through an opaque asm once after load, so LLVM cannot rematerialize the
// global loads inside the 66-tick loop (the R5 failure mode: VGPR=64,
// weights re-fetched from L2 every tick).
// ---------------------------------------------------------------------------
__global__ __launch_bounds__(64, 1) void trace_mlp_kernel(
    const float* __restrict__ fv,
    const float* __restrict__ tWih, const float* __restrict__ tWhh,
    const float* __restrict__ tb,
    const float* __restrict__ L1W, const float* __restrict__ L1b,
    const float* __restrict__ L2W, const float* __restrict__ L2b,
    const float* __restrict__ L3W, const float* __restrict__ L3b,
    const float* __restrict__ L4W, const float* __restrict__ L4b,
    float* __restrict__ out)
{
    __shared__ __align__(16) float xrow[640];
    __shared__ __align__(16) float m1[128];
    __shared__ __align__(16) float m2b[256];
    __shared__ __align__(16) float m3[64];

    const int lane = threadIdx.x;
    const int ti = blockIdx.x;

    {
        const float4* src = (const float4*)(fv + (size_t)ti * 640);
        float4* dst = (float4*)xrow;
        for (int i = lane; i < 160; i += 64) dst[i] = src[i];
    }
    __asm__ __volatile__("" ::: "memory");   // same-wave DS ordering

    const int g = (lane < 30) ? (lane / 10) : 2;   // layer this lane serves
    const int j = lane % 10;                        // hidden unit

    // weight pairs for this lane's layer/unit: A=(i,f), B=(g,o)
    const float* WiL = tWih + g * 400;
    const float* WhL = tWhh + g * 400;
    const float* bL  = tb + g * 40;
    DECLW(wxA); DECLW(wxB); DECLW(whA); DECLW(whB);
    LOADW_PAIR(wxA, WiL + j * 10,        WiL + (10 + j) * 10);
    LOADW_PAIR(wxB, WiL + (20 + j) * 10, WiL + (30 + j) * 10);
    LOADW_PAIR(whA, WhL + j * 10,        WhL + (10 + j) * 10);
    LOADW_PAIR(whB, WhL + (20 + j) * 10, WhL + (30 + j) * 10);
    v2f bA = (v2f){bL[j], bL[10 + j]};
    v2f bB = (v2f){bL[20 + j], bL[30 + j]};
    // make every weight register opaque (non-rematerializable)
    PINW(wxA); PINW(wxB); PINW(whA); PINW(whB);
    PIN(bA); PIN(bB);

    DECLU(u0); DECLU(u1); DECLU(u2);    // uniform h state (readlane-produced)
    ZEROU(u0); ZEROU(u1); ZEROU(u2);
    float c = 0.0f, h = 0.0f;
    const int tlo = g, thi = 63 + g;    // activity window for this lane's layer
    const bool g0 = (g == 0), g1 = (g == 1);

    DECL5(xc); DECL5(xn);
    LOAD5(xc, xrow);

    for (int tau = 0; tau < 66; ++tau) {
        const int tn = (tau + 1 < 64) ? (tau + 1) : 63;
        LOAD5(xn, xrow + tn * 10);      // prefetch; consumed next tick

        // per-lane input vector: layer0 <- x(t), layer1 <- u0, layer2 <- u1
        const float in0 = g0 ? xc_0.x : (g1 ? u00 : u10);
        const float in1 = g0 ? xc_0.y : (g1 ? u01 : u11);
        const float in2 = g0 ? xc_1.x : (g1 ? u02 : u12);
        const float in3 = g0 ? xc_1.y : (g1 ? u03 : u13);
        const float in4 = g0 ? xc_2.x : (g1 ? u04 : u14);
        const float in5 = g0 ? xc_2.y : (g1 ? u05 : u15);
        const float in6 = g0 ? xc_3.x : (g1 ? u06 : u16);
        const float in7 = g0 ? xc_3.y : (g1 ? u07 : u17);
        const float in8 = g0 ? xc_4.x : (g1 ? u08 : u18);
        const float in9 = g0 ? xc_4.y : (g1 ? u09 : u19);
        // per-lane hidden vector: own layer's h
        const float hd0 = g0 ? u00 : (g1 ? u10 : u20);
        const float hd1 = g0 ? u01 : (g1 ? u11 : u21);
        const float hd2 = g0 ? u02 : (g1 ? u12 : u22);
        const float hd3 = g0 ? u03 : (g1 ? u13 : u23);
        const float hd4 = g0 ? u04 : (g1 ? u14 : u24);
        const float hd5 = g0 ? u05 : (g1 ? u15 : u25);
        const float hd6 = g0 ? u06 : (g1 ? u16 : u26);
        const float hd7 = g0 ? u07 : (g1 ? u17 : u27);
        const float hd8 = g0 ? u08 : (g1 ? u18 : u28);
        const float hd9 = g0 ? u09 : (g1 ? u19 : u29);

        v2f gA = bA, gB = bB;
        PKDOT(gA, wxA, in); PKDOT(gB, wxB, in);
        PKDOT(gA, whA, hd); PKDOT(gB, whB, hd);

        const float ai = sigmoid_f(gA.x);
        const float af = sigmoid_f(gA.y);
        const float ag = tanh_f(gB.x);
        const float ao = sigmoid_f(gB.y);
        const float cn = af * c + ai * ag;
        const float hn = ao * tanh_f(cn);
        const bool act = (tau >= tlo) && (tau <= thi);
        c = act ? cn : c;
        h = act ? hn : h;

        u00 = readlane_f(h, 0); u01 = readlane_f(h, 1); u02 = readlane_f(h, 2);
        u03 = readlane_f(h, 3); u04 = readlane_f(h, 4); u05 = readlane_f(h, 5);
        u06 = readlane_f(h, 6); u07 = readlane_f(h, 7); u08 = readlane_f(h, 8);
        u09 = readlane_f(h, 9);
        u10 = readlane_f(h, 10); u11 = readlane_f(h, 11); u12 = readlane_f(h, 12);
        u13 = readlane_f(h, 13); u14 = readlane_f(h, 14); u15 = readlane_f(h, 15);
        u16 = readlane_f(h, 16); u17 = readlane_f(h, 17); u18 = readlane_f(h, 18);
        u19 = readlane_f(h, 19);
        u20 = readlane_f(h, 20); u21 = readlane_f(h, 21); u22 = readlane_f(h, 22);
        u23 = readlane_f(h, 23); u24 = readlane_f(h, 24); u25 = readlane_f(h, 25);
        u26 = readlane_f(h, 26); u27 = readlane_f(h, 27); u28 = readlane_f(h, 28);
        u29 = readlane_f(h, 29);

        CP5(xc, xn);
    }

    // tv = h_n(layer2) + h_n(layer1): uniform
    DECLU(tv);
    tv0 = u10 + u20; tv1 = u11 + u21; tv2 = u12 + u22; tv3 = u13 + u23;
    tv4 = u14 + u24; tv5 = u15 + u25; tv6 = u16 + u26; tv7 = u17 + u27;
    tv8 = u18 + u28; tv9 = u19 + u29;

    // ---- fused per-row MLP: 10 ->128 ->256 ->64 ->7 ----
    {
        DECL5(w1a); DECL5(w1b);
        LOAD5(w1a, L1W + lane * 10);
        LOAD5(w1b, L1W + (lane + 64) * 10);
        float a0 = L1b[lane] + DOTU(w1a, tv);
        float a1 = L1b[lane + 64] + DOTU(w1b, tv);
        m1[lane] = lrelu(a0);
        m1[lane + 64] = lrelu(a1);
    }
    __asm__ __volatile__("" ::: "memory");
    {
        float acc0 = L2b[lane];
        float acc1 = L2b[lane + 64];
        float acc2 = L2b[lane + 128];
        float acc3 = L2b[lane + 192];
        for (int k = 0; k < 128; k += 4) {
            float4 hv = *(const float4*)(m1 + k);
            float4 w0 = *(const float4*)(L2W + (size_t)lane * 128 + k);
            float4 w1 = *(const float4*)(L2W + (size_t)(lane + 64) * 128 + k);
            float4 w2 = *(const float4*)(L2W + (size_t)(lane + 128) * 128 + k);
            float4 w3 = *(const float4*)(L2W + (size_t)(lane + 192) * 128 + k);
            acc0 = fmaf(w0.x, hv.x, acc0); acc0 = fmaf(w0.y, hv.y, acc0);
            acc0 = fmaf(w0.z, hv.z, acc0); acc0 = fmaf(w0.w, hv.w, acc0);
            acc1 = fmaf(w1.x, hv.x, acc1); acc1 = fmaf(w1.y, hv.y, acc1);
            acc1 = fmaf(w1.z, hv.z, acc1); acc1 = fmaf(w1.w, hv.w, acc1);
            acc2 = fmaf(w2.x, hv.x, acc2); acc2 = fmaf(w2.y, hv.y, acc2);
            acc2 = fmaf(w2.z, hv.z, acc2); acc2 = fmaf(w2.w, hv.w, acc2);
            acc3 = fmaf(w3.x, hv.x, acc3); acc3 = fmaf(w3.y, hv.y, acc3);
            acc3 = fmaf(w3.z, hv.z, acc3); acc3 = fmaf(w3.w, hv.w, acc3);
        }
        m2b[lane] = lrelu(acc0);
        m2b[lane + 64] = lrelu(acc1);
        m2b[lane + 128] = lrelu(acc2);
        m2b[lane + 192] = lrelu(acc3);
    }
    __asm__ __volatile__("" ::: "memory");
    {
        float acc = L3b[lane];
        for (int k = 0; k < 256; k += 4) {
            float4 hv = *(const float4*)(m2b + k);
            float4 wv = *(const float4*)(L3W + (size_t)lane * 256 + k);
            acc = fmaf(wv.x, hv.x, acc);
            acc = fmaf(wv.y, hv.y, acc);
            acc = fmaf(wv.z, hv.z, acc);
            acc = fmaf(wv.w, hv.w, acc);
        }
        m3[lane] = lrelu(acc);
    }
    __asm__ __volatile__("" ::: "memory");
    if (lane < 7) {
        float acc = L4b[lane];
        #pragma unroll
        for (int k = 0; k < 64; k += 4) {
            float4 hv = *(const float4*)(m3 + k);
            float4 wv = *(const float4*)(L4W + lane * 64 + k);
            acc = fmaf(wv.x, hv.x, acc);
            acc = fmaf(wv.y, hv.y, acc);
            acc = fmaf(wv.z, hv.z, acc);
            acc = fmaf(wv.w, hv.w, acc);
        }
        out[ti * 7 + lane] = acc;
    }
}

// ---------------------------------------------------------------------------
extern "C" void kernel_launch(void* const* d_in, const int* in_sizes, int n_in,
                              void* d_out, int out_size, void* d_ws, size_t ws_size,
                              hipStream_t stream)
{
    const float* data_in = (const float*)d_in[0];
    const float* W1 = (const float*)d_in[1];
    const float* b1 = (const float*)d_in[2];
    const float* W2 = (const float*)d_in[3];
    const float* b2 = (const float*)d_in[4];
    const float* W3 = (const float*)d_in[5];
    const float* b3 = (const float*)d_in[6];
    const float* fWih = (const float*)d_in[7];
    const float* fWhh = (const float*)d_in[8];
    const float* fb = (const float*)d_in[9];
    const float* tWih = (const float*)d_in[10];
    const float* tWhh = (const float*)d_in[11];
    const float* tb = (const float*)d_in[12];
    const float* L1W = (const float*)d_in[13];
    const float* L1b = (const float*)d_in[14];
    const float* L2W = (const float*)d_in[15];
    const float* L2b = (const float*)d_in[16];
    const float* L3W = (const float*)d_in[17];
    const float* L3b = (const float*)d_in[18];
    const float* L4W = (const float*)d_in[19];
    const float* L4b = (const float*)d_in[20];

    float* xseq = (float*)d_ws;            // 4096*180 floats
    float* fv = xseq + 4096 * 180;         // 4096*10 floats
    float* outp = (float*)d_out;           // 64*7 floats

    conv_kernel<<<4096, 256, 0, stream>>>(data_in, W1, b1, W2, b2, W3, b3, xseq);
    flow_lstm_kernel<<<256, 256, 0, stream>>>(xseq, fWih, fWhh, fb, fv);
    trace_mlp_kernel<<<64, 64, 0, stream>>>(fv, tWih, tWhh, tb,
                                            L1W, L1b, L2W, L2b, L3W, L3b,
                                            L4W, L4b, outp);
}

// Round 7
// 197.961 us; speedup vs baseline: 1.0162x; 1.0117x over previous
//
#include <hip/hip_runtime.h>
#include <math.h>

#define LEAK 0.01f

typedef float v2f __attribute__((ext_vector_type(2)));

// opaque pass-through: result of asm cannot be rematerialized by LLVM
#define PIN(x) asm("" : "+v"(x))

__device__ __forceinline__ float lrelu(float x) { return fmaxf(x, LEAK * x); }
__device__ __forceinline__ float fast_rcp(float x) { return __builtin_amdgcn_rcpf(x); }
__device__ __forceinline__ float sigmoid_f(float x) {
    return fast_rcp(1.0f + exp2f(-1.44269504f * x));
}
__device__ __forceinline__ float tanh_f(float x) {
    return 2.0f * fast_rcp(1.0f + exp2f(-2.88539008f * x)) - 1.0f;
}
__device__ __forceinline__ float readlane_f(float v, int l) {
    return __int_as_float(__builtin_amdgcn_readlane(__float_as_int(v), l));
}

// ---- named-scalar helpers (NO arrays: guarantees SROA/register residency) ----
#define DECL5(p) v2f p##_0, p##_1, p##_2, p##_3, p##_4
#define LOAD5(p, src) do { const v2f* _s5 = (const v2f*)(src); \
    p##_0 = _s5[0]; p##_1 = _s5[1]; p##_2 = _s5[2]; p##_3 = _s5[3]; p##_4 = _s5[4]; } while (0)
#define CP5(d, s) do { d##_0 = s##_0; d##_1 = s##_1; d##_2 = s##_2; d##_3 = s##_3; d##_4 = s##_4; } while (0)
#define ZERO5(p) do { p##_0 = (v2f){0.f,0.f}; p##_1 = (v2f){0.f,0.f}; p##_2 = (v2f){0.f,0.f}; \
    p##_3 = (v2f){0.f,0.f}; p##_4 = (v2f){0.f,0.f}; } while (0)
// packed dot over 5 v2f pairs (v_pk_fma_f32)
#define DOT5(w, x) ((w##_0 * x##_0 + w##_1 * x##_1) + (w##_2 * x##_2 + w##_3 * x##_3) + w##_4 * x##_4)

// uniform 10-vector as named scalars
#define DECLU(u) float u##0, u##1, u##2, u##3, u##4, u##5, u##6, u##7, u##8, u##9
#define ZEROU(u) do { u##0=u##1=u##2=u##3=u##4=u##5=u##6=u##7=u##8=u##9=0.0f; } while (0)
// dot: VGPR weight pairs x uniform vector
#define DOTU(w, u) (fmaf(w##_0.x, u##0, fmaf(w##_0.y, u##1, fmaf(w##_1.x, u##2, fmaf(w##_1.y, u##3, w##_2.x * u##4)))) \
                  + fmaf(w##_2.y, u##5, fmaf(w##_3.x, u##6, fmaf(w##_3.y, u##7, fmaf(w##_4.x, u##8, w##_4.y * u##9)))))

// 10 weight-pair registers (one v2f per input element)
#define DECLW(p) v2f p##0, p##1, p##2, p##3, p##4, p##5, p##6, p##7, p##8, p##9
#define LOADW_PAIR(p, q0, q1) do { \
    p##0 = (v2f){(q0)[0], (q1)[0]}; p##1 = (v2f){(q0)[1], (q1)[1]}; \
    p##2 = (v2f){(q0)[2], (q1)[2]}; p##3 = (v2f){(q0)[3], (q1)[3]}; \
    p##4 = (v2f){(q0)[4], (q1)[4]}; p##5 = (v2f){(q0)[5], (q1)[5]}; \
    p##6 = (v2f){(q0)[6], (q1)[6]}; p##7 = (v2f){(q0)[7], (q1)[7]}; \
    p##8 = (v2f){(q0)[8], (q1)[8]}; p##9 = (v2f){(q0)[9], (q1)[9]}; } while (0)
#define PINW(p) do { PIN(p##0); PIN(p##1); PIN(p##2); PIN(p##3); PIN(p##4); \
    PIN(p##5); PIN(p##6); PIN(p##7); PIN(p##8); PIN(p##9); } while (0)
// acc += Σ_k w_k * splat(s_k)   (10 pk-fma)
#define PKDOT(acc, w, s) do { \
    acc += w##0 * (v2f){s##0, s##0}; acc += w##1 * (v2f){s##1, s##1}; \
    acc += w##2 * (v2f){s##2, s##2}; acc += w##3 * (v2f){s##3, s##3}; \
    acc += w##4 * (v2f){s##4, s##4}; acc += w##5 * (v2f){s##5, s##5}; \
    acc += w##6 * (v2f){s##6, s##6}; acc += w##7 * (v2f){s##7, s##7}; \
    acc += w##8 * (v2f){s##8, s##8}; acc += w##9 * (v2f){s##9, s##9}; } while (0)

#define L1C 508
#define L1P 170
#define L2C 166
#define L2P 56
#define L3C 52
#define L3P 18
#define TT 18

// ---------------------------------------------------------------------------
// K1: per-flow conv1d x3 (+lrelu, +maxpool3 fused) — unchanged.
// ---------------------------------------------------------------------------
__global__ __launch_bounds__(256, 4) void conv_kernel(
    const float* __restrict__ in,
    const float* __restrict__ W1, const float* __restrict__ b1,
    const float* __restrict__ W2, const float* __restrict__ b2,
    const float* __restrict__ W3, const float* __restrict__ b3,
    float* __restrict__ xseq)
{
    __shared__ __align__(16) float xsraw[24 + 1536 + 24];
    __shared__ __align__(16) float y1raw[16 + L1P * 10 + 32];
    __shared__ __align__(16) float y2raw[8 + L2P * 6 + 24];
    float* xs = xsraw + 24;
    float* y1 = y1raw + 16;
    float* y2 = y2raw + 8;

    const int tid = threadIdx.x;
    const int b = blockIdx.x;

    {
        const float4* src = (const float4*)(in + (size_t)b * 1536);
        float4* dst4 = (float4*)xs;
        for (int i = tid; i < 384; i += 256) dst4[i] = src[i];
    }
    __syncthreads();

    // ---- conv1 (3->10, k5) + lrelu + pool3 -> y1[170][10] ----
    {
        const int co = tid % 10;
        const int ob = tid / 10;
        if (tid < 250) {
            float w[15];
            #pragma unroll
            for (int q = 0; q < 15; ++q) w[q] = W1[co * 15 + q];
            const float bias = b1[co];
            const int o0 = ob * 7;
            int sb = 3 * o0 - 1;
            float win[21];
            #pragma unroll
            for (int q = 0; q < 21; ++q) win[q] = xs[3 * sb + q];
            #pragma unroll
            for (int r = 0; r < 7; ++r) {
                const int o = o0 + r;
                if (o < L1P) {
                    float a0 = bias, a1 = bias, a2 = bias;
                    #pragma unroll
                    for (int p = 0; p < 3; ++p) {
                        #pragma unroll
                        for (int k = 0; k < 5; ++k) {
                            const float wv = w[p * 5 + k];
                            a0 = fmaf(wv, win[3 * k + p], a0);
                            a1 = fmaf(wv, win[3 * (k + 1) + p], a1);
                            a2 = fmaf(wv, win[3 * (k + 2) + p], a2);
                        }
                    }
                    float best = -3.0e38f;
                    if (sb >= 0)        best = fmaxf(best, lrelu(a0));
                    best = fmaxf(best, lrelu(a1));
                    if (sb + 2 < L1C)   best = fmaxf(best, lrelu(a2));
                    y1[o * 10 + co] = best;
                }
                if (r < 6 && o + 1 < L1P) {
                    #pragma unroll
                    for (int q = 0; q < 12; ++q) win[q] = win[q + 9];
                    #pragma unroll
                    for (int q = 0; q < 9; ++q) win[12 + q] = xs[3 * sb + 21 + q];
                    sb += 3;
                }
            }
        }
    }
    __syncthreads();

    // ---- conv2 (10->5, k5) + lrelu + pool3 -> y2[56][6-stride] ----
    {
        const int co = tid % 5;
        const int ob = tid / 5;
        v2f wv2[25];
        #pragma unroll
        for (int c2 = 0; c2 < 5; ++c2)
            #pragma unroll
            for (int k = 0; k < 5; ++k)
                wv2[c2 * 5 + k] = (v2f){W2[co * 50 + (2 * c2) * 5 + k],
                                        W2[co * 50 + (2 * c2 + 1) * 5 + k]};
        const float bias = b2[co];
        if (tid < 255) {
            for (int r = 0; r < 2; ++r) {
                const int o = ob + 51 * r;
                if (o < L2P) {
                    const int t0 = 3 * o - 1;
                    v2f v0 = {0.f, 0.f}, v1 = {0.f, 0.f}, v2 = {0.f, 0.f};
                    #pragma unroll
                    for (int m = 0; m < 7; ++m) {
                        v2f rows5[5];
                        const v2f* pr = (const v2f*)(y1 + (t0 + m) * 10);
                        #pragma unroll
                        for (int c2 = 0; c2 < 5; ++c2) rows5[c2] = pr[c2];
                        #pragma unroll
                        for (int c2 = 0; c2 < 5; ++c2) {
                            if (m < 5)            v0 += wv2[c2 * 5 + m] * rows5[c2];
                            if (m >= 1 && m <= 5) v1 += wv2[c2 * 5 + m - 1] * rows5[c2];
                            if (m >= 2)           v2 += wv2[c2 * 5 + m - 2] * rows5[c2];
                        }
                    }
                    const float a0 = bias + v0.x + v0.y;
                    const float a1 = bias + v1.x + v1.y;
                    const float a2 = bias + v2.x + v2.y;
                    float best = -3.0e38f;
                    if (t0 >= 0)        best = fmaxf(best, lrelu(a0));
                    best = fmaxf(best, lrelu(a1));
                    if (t0 + 2 < L2C)   best = fmaxf(best, lrelu(a2));
                    y2[o * 6 + co] = best;
                }
            }
        }
    }
    __syncthreads();

    // ---- conv3 (5->10, k5) + lrelu + pool3 -> xseq ----
    {
        const int co = tid % 10;
        const int o = tid / 10;
        if (o < L3P) {
            v2f wv3[10];
            float ws3[5];
            #pragma unroll
            for (int c2 = 0; c2 < 2; ++c2)
                #pragma unroll
                for (int k = 0; k < 5; ++k)
                    wv3[c2 * 5 + k] = (v2f){W3[co * 25 + (2 * c2) * 5 + k],
                                            W3[co * 25 + (2 * c2 + 1) * 5 + k]};
            #pragma unroll
            for (int k = 0; k < 5; ++k) ws3[k] = W3[co * 25 + 20 + k];
            const float bias = b3[co];
            const int t0 = 3 * o - 1;
            v2f v0 = {0.f, 0.f}, v1 = {0.f, 0.f}, v2 = {0.f, 0.f};
            float s0 = 0.f, s1 = 0.f, s2 = 0.f;
            #pragma unroll
            for (int m = 0; m < 7; ++m) {
                const float* base = y2 + (t0 + m) * 6;
                v2f ra0 = ((const v2f*)base)[0];
                v2f ra1 = ((const v2f*)base)[1];
                float rcm = base[4];
                if (m < 5) {
                    v0 += wv3[m] * ra0; v0 += wv3[5 + m] * ra1;
                    s0 = fmaf(ws3[m], rcm, s0);
                }
                if (m >= 1 && m <= 5) {
                    v1 += wv3[m - 1] * ra0; v1 += wv3[5 + m - 1] * ra1;
                    s1 = fmaf(ws3[m - 1], rcm, s1);
                }
                if (m >= 2) {
                    v2 += wv3[m - 2] * ra0; v2 += wv3[5 + m - 2] * ra1;
                    s2 = fmaf(ws3[m - 2], rcm, s2);
                }
            }
            const float a0 = bias + s0 + v0.x + v0.y;
            const float a1 = bias + s1 + v1.x + v1.y;
            const float a2 = bias + s2 + v2.x + v2.y;
            float best = -3.0e38f;
            if (t0 >= 0)        best = fmaxf(best, lrelu(a0));
            best = fmaxf(best, lrelu(a1));
            if (t0 + 2 < L3C)   best = fmaxf(best, lrelu(a2));
            xseq[(size_t)b * 180 + o * 10 + co] = best;
        }
    }
}

// ---------------------------------------------------------------------------
// K2: flow LSTM (3 layers, T=18, H=10) over 4096 flows.
// waves_per_eu(1,1): grid is 1024 waves = exactly 1 wave/SIMD chip-wide, so
// occupancy target 1 costs nothing and lifts the RA's 64-VGPR pressure clamp
// (which was rematerializing the 80-VGPR weight set from L2 every step).
// ---------------------------------------------------------------------------
__global__ __launch_bounds__(256) __attribute__((amdgpu_waves_per_eu(1, 1)))
void flow_lstm_kernel(
    const float* __restrict__ xseq,
    const float* __restrict__ fWih, const float* __restrict__ fWhh,
    const float* __restrict__ fb,
    float* __restrict__ fv)
{
    __shared__ __align__(16) float sbuf[3][16 * 18 * 10];
    const int tid = threadIdx.x;
    const int blk = blockIdx.x;

    {
        const float* src = xseq + (size_t)blk * 2880;
        for (int i = tid; i < 2880; i += 256) sbuf[0][i] = src[i];
    }
    __syncthreads();

    const int el = tid >> 4;
    const int j = tid & 15;
    const int jj = (j < 10) ? j : 0;
    const int base = el * 180;
    const int lane = tid & 63;
    const int gbase = lane & 48;

    float fv_acc = 0.0f;

    for (int l = 0; l < 3; ++l) {
        const float* Wi = fWih + l * 400;
        const float* Wh = fWhh + l * 400;
        const float* bb = fb + l * 40;
        DECL5(wii); DECL5(wif); DECL5(wig); DECL5(wio);
        DECL5(whi); DECL5(whf); DECL5(whg); DECL5(who);
        LOAD5(wii, Wi + jj * 10);
        LOAD5(wif, Wi + (10 + jj) * 10);
        LOAD5(wig, Wi + (20 + jj) * 10);
        LOAD5(wio, Wi + (30 + jj) * 10);
        LOAD5(whi, Wh + jj * 10);
        LOAD5(whf, Wh + (10 + jj) * 10);
        LOAD5(whg, Wh + (20 + jj) * 10);
        LOAD5(who, Wh + (30 + jj) * 10);
        const float bi = bb[jj], bf = bb[10 + jj], bg = bb[20 + jj], bo = bb[30 + jj];

        const float* inb = sbuf[l];
        float* outb = sbuf[(l + 1) % 3];
        float c = 0.0f, hj = 0.0f;
        DECL5(hv); ZERO5(hv);
        DECL5(xc); DECL5(xn);
        LOAD5(xc, inb + base);

        for (int t = 0; t < TT; ++t) {
            if (t + 1 < TT) LOAD5(xn, inb + base + (t + 1) * 10);
            v2f ti_ = DOT5(wii, xc) + DOT5(whi, hv);
            v2f tf_ = DOT5(wif, xc) + DOT5(whf, hv);
            v2f tg_ = DOT5(wig, xc) + DOT5(whg, hv);
            v2f to_ = DOT5(wio, xc) + DOT5(who, hv);
            const float ai = sigmoid_f(bi + ti_.x + ti_.y);
            const float af = sigmoid_f(bf + tf_.x + tf_.y);
            const float ag = tanh_f(bg + tg_.x + tg_.y);
            const float ao = sigmoid_f(bo + to_.x + to_.y);
            c = af * c + ai * ag;
            hj = ao * tanh_f(c);
            if (j < 10) outb[base + t * 10 + j] = hj;
            hv_0 = (v2f){__shfl(hj, gbase + 0), __shfl(hj, gbase + 1)};
            hv_1 = (v2f){__shfl(hj, gbase + 2), __shfl(hj, gbase + 3)};
            hv_2 = (v2f){__shfl(hj, gbase + 4), __shfl(hj, gbase + 5)};
            hv_3 = (v2f){__shfl(hj, gbase + 6), __shfl(hj, gbase + 7)};
            hv_4 = (v2f){__shfl(hj, gbase + 8), __shfl(hj, gbase + 9)};
            CP5(xc, xn);
        }
        if (l >= 1) fv_acc += hj;
        __asm__ __volatile__("" ::: "memory");
    }
    if (j < 10) fv[(size_t)(blk * 16 + el) * 10 + j] = fv_acc;
}

// ---------------------------------------------------------------------------
// K3: trace LSTM (3 layers, T=64, H=10), one wave per trace row, + fused MLP.
// DS-free recurrence + PINned weights + waves_per_eu(1,1): the scheduler's
// default occupancy target of 8 waves/EU was clamping VGPR pressure to 64
// (observed: VGPR_Count=64=512/8) and rematerializing the 84-VGPR weight set
// from L2 inside the 66-tick loop. Occupancy target 1 lifts the clamp.
// ---------------------------------------------------------------------------
__global__ __launch_bounds__(64) __attribute__((amdgpu_waves_per_eu(1, 1)))
void trace_mlp_kernel(
    const float* __restrict__ fv,
    const float* __restrict__ tWih, const float* __restrict__ tWhh,
    const float* __restrict__ tb,
    const float* __restrict__ L1W, const float* __restrict__ L1b,
    const float* __restrict__ L2W, const float* __restrict__ L2b,
    const float* __restrict__ L3W, const float* __restrict__ L3b,
    const float* __restrict__ L4W, const float* __restrict__ L4b,
    float* __restrict__ out)
{
    __shared__ __align__(16) float xrow[640];
    __shared__ __align__(16) float m1[128];
    __shared__ __align__(16) float m2b[256];
    __shared__ __align__(16) float m3[64];

    const int lane = threadIdx.x;
    const int ti = blockIdx.x;

    {
        const float4* src = (const float4*)(fv + (size_t)ti * 640);
        float4* dst = (float4*)xrow;
        for (int i = lane; i < 160; i += 64) dst[i] = src[i];
    }
    __asm__ __volatile__("" ::: "memory");   // same-wave DS ordering

    const int g = (lane < 30) ? (lane / 10) : 2;   // layer this lane serves
    const int j = lane % 10;                        // hidden unit

    // weight pairs for this lane's layer/unit: A=(i,f), B=(g,o)
    const float* WiL = tWih + g * 400;
    const float* WhL = tWhh + g * 400;
    const float* bL  = tb + g * 40;
    DECLW(wxA); DECLW(wxB); DECLW(whA); DECLW(whB);
    LOADW_PAIR(wxA, WiL + j * 10,        WiL + (10 + j) * 10);
    LOADW_PAIR(wxB, WiL + (20 + j) * 10, WiL + (30 + j) * 10);
    LOADW_PAIR(whA, WhL + j * 10,        WhL + (10 + j) * 10);
    LOADW_PAIR(whB, WhL + (20 + j) * 10, WhL + (30 + j) * 10);
    v2f bA = (v2f){bL[j], bL[10 + j]};
    v2f bB = (v2f){bL[20 + j], bL[30 + j]};
    // make every weight register opaque (non-rematerializable)
    PINW(wxA); PINW(wxB); PINW(whA); PINW(whB);
    PIN(bA); PIN(bB);

    DECLU(u0); DECLU(u1); DECLU(u2);    // uniform h state (readlane-produced)
    ZEROU(u0); ZEROU(u1); ZEROU(u2);
    float c = 0.0f, h = 0.0f;
    const int tlo = g, thi = 63 + g;    // activity window for this lane's layer
    const bool g0 = (g == 0), g1 = (g == 1);

    DECL5(xc); DECL5(xn);
    LOAD5(xc, xrow);

    for (int tau = 0; tau < 66; ++tau) {
        const int tn = (tau + 1 < 64) ? (tau + 1) : 63;
        LOAD5(xn, xrow + tn * 10);      // prefetch; consumed next tick

        // per-lane input vector: layer0 <- x(t), layer1 <- u0, layer2 <- u1
        const float in0 = g0 ? xc_0.x : (g1 ? u00 : u10);
        const float in1 = g0 ? xc_0.y : (g1 ? u01 : u11);
        const float in2 = g0 ? xc_1.x : (g1 ? u02 : u12);
        const float in3 = g0 ? xc_1.y : (g1 ? u03 : u13);
        const float in4 = g0 ? xc_2.x : (g1 ? u04 : u14);
        const float in5 = g0 ? xc_2.y : (g1 ? u05 : u15);
        const float in6 = g0 ? xc_3.x : (g1 ? u06 : u16);
        const float in7 = g0 ? xc_3.y : (g1 ? u07 : u17);
        const float in8 = g0 ? xc_4.x : (g1 ? u08 : u18);
        const float in9 = g0 ? xc_4.y : (g1 ? u09 : u19);
        // per-lane hidden vector: own layer's h
        const float hd0 = g0 ? u00 : (g1 ? u10 : u20);
        const float hd1 = g0 ? u01 : (g1 ? u11 : u21);
        const float hd2 = g0 ? u02 : (g1 ? u12 : u22);
        const float hd3 = g0 ? u03 : (g1 ? u13 : u23);
        const float hd4 = g0 ? u04 : (g1 ? u14 : u24);
        const float hd5 = g0 ? u05 : (g1 ? u15 : u25);
        const float hd6 = g0 ? u06 : (g1 ? u16 : u26);
        const float hd7 = g0 ? u07 : (g1 ? u17 : u27);
        const float hd8 = g0 ? u08 : (g1 ? u18 : u28);
        const float hd9 = g0 ? u09 : (g1 ? u19 : u29);

        v2f gA = bA, gB = bB;
        PKDOT(gA, wxA, in); PKDOT(gB, wxB, in);
        PKDOT(gA, whA, hd); PKDOT(gB, whB, hd);

        const float ai = sigmoid_f(gA.x);
        const float af = sigmoid_f(gA.y);
        const float ag = tanh_f(gB.x);
        const float ao = sigmoid_f(gB.y);
        const float cn = af * c + ai * ag;
        const float hn = ao * tanh_f(cn);
        const bool act = (tau >= tlo) && (tau <= thi);
        c = act ? cn : c;
        h = act ? hn : h;

        u00 = readlane_f(h, 0); u01 = readlane_f(h, 1); u02 = readlane_f(h, 2);
        u03 = readlane_f(h, 3); u04 = readlane_f(h, 4); u05 = readlane_f(h, 5);
        u06 = readlane_f(h, 6); u07 = readlane_f(h, 7); u08 = readlane_f(h, 8);
        u09 = readlane_f(h, 9);
        u10 = readlane_f(h, 10); u11 = readlane_f(h, 11); u12 = readlane_f(h, 12);
        u13 = readlane_f(h, 13); u14 = readlane_f(h, 14); u15 = readlane_f(h, 15);
        u16 = readlane_f(h, 16); u17 = readlane_f(h, 17); u18 = readlane_f(h, 18);
        u19 = readlane_f(h, 19);
        u20 = readlane_f(h, 20); u21 = readlane_f(h, 21); u22 = readlane_f(h, 22);
        u23 = readlane_f(h, 23); u24 = readlane_f(h, 24); u25 = readlane_f(h, 25);
        u26 = readlane_f(h, 26); u27 = readlane_f(h, 27); u28 = readlane_f(h, 28);
        u29 = readlane_f(h, 29);

        CP5(xc, xn);
    }

    // tv = h_n(layer2) + h_n(layer1): uniform
    DECLU(tv);
    tv0 = u10 + u20; tv1 = u11 + u21; tv2 = u12 + u22; tv3 = u13 + u23;
    tv4 = u14 + u24; tv5 = u15 + u25; tv6 = u16 + u26; tv7 = u17 + u27;
    tv8 = u18 + u28; tv9 = u19 + u29;

    // ---- fused per-row MLP: 10 ->128 ->256 ->64 ->7 ----
    {
        DECL5(w1a); DECL5(w1b);
        LOAD5(w1a, L1W + lane * 10);
        LOAD5(w1b, L1W + (lane + 64) * 10);
        float a0 = L1b[lane] + DOTU(w1a, tv);
        float a1 = L1b[lane + 64] + DOTU(w1b, tv);
        m1[lane] = lrelu(a0);
        m1[lane + 64] = lrelu(a1);
    }
    __asm__ __volatile__("" ::: "memory");
    {
        float acc0 = L2b[lane];
        float acc1 = L2b[lane + 64];
        float acc2 = L2b[lane + 128];
        float acc3 = L2b[lane + 192];
        for (int k = 0; k < 128; k += 4) {
            float4 hv = *(const float4*)(m1 + k);
            float4 w0 = *(const float4*)(L2W + (size_t)lane * 128 + k);
            float4 w1 = *(const float4*)(L2W + (size_t)(lane + 64) * 128 + k);
            float4 w2 = *(const float4*)(L2W + (size_t)(lane + 128) * 128 + k);
            float4 w3 = *(const float4*)(L2W + (size_t)(lane + 192) * 128 + k);
            acc0 = fmaf(w0.x, hv.x, acc0); acc0 = fmaf(w0.y, hv.y, acc0);
            acc0 = fmaf(w0.z, hv.z, acc0); acc0 = fmaf(w0.w, hv.w, acc0);
            acc1 = fmaf(w1.x, hv.x, acc1); acc1 = fmaf(w1.y, hv.y, acc1);
            acc1 = fmaf(w1.z, hv.z, acc1); acc1 = fmaf(w1.w, hv.w, acc1);
            acc2 = fmaf(w2.x, hv.x, acc2); acc2 = fmaf(w2.y, hv.y, acc2);
            acc2 = fmaf(w2.z, hv.z, acc2); acc2 = fmaf(w2.w, hv.w, acc2);
            acc3 = fmaf(w3.x, hv.x, acc3); acc3 = fmaf(w3.y, hv.y, acc3);
            acc3 = fmaf(w3.z, hv.z, acc3); acc3 = fmaf(w3.w, hv.w, acc3);
        }
        m2b[lane] = lrelu(acc0);
        m2b[lane + 64] = lrelu(acc1);
        m2b[lane + 128] = lrelu(acc2);
        m2b[lane + 192] = lrelu(acc3);
    }
    __asm__ __volatile__("" ::: "memory");
    {
        float acc = L3b[lane];
        for (int k = 0; k < 256; k += 4) {
            float4 hv = *(const float4*)(m2b + k);
            float4 wv = *(const float4*)(L3W + (size_t)lane * 256 + k);
            acc = fmaf(wv.x, hv.x, acc);
            acc = fmaf(wv.y, hv.y, acc);
            acc = fmaf(wv.z, hv.z, acc);
            acc = fmaf(wv.w, hv.w, acc);
        }
        m3[lane] = lrelu(acc);
    }
    __asm__ __volatile__("" ::: "memory");
    if (lane < 7) {
        float acc = L4b[lane];
        #pragma unroll
        for (int k = 0; k < 64; k += 4) {
            float4 hv = *(const float4*)(m3 + k);
            float4 wv = *(const float4*)(L4W + lane * 64 + k);
            acc = fmaf(wv.x, hv.x, acc);
            acc = fmaf(wv.y, hv.y, acc);
            acc = fmaf(wv.z, hv.z, acc);
            acc = fmaf(wv.w, hv.w, acc);
        }
        out[ti * 7 + lane] = acc;
    }
}

// ---------------------------------------------------------------------------
extern "C" void kernel_launch(void* const* d_in, const int* in_sizes, int n_in,
                              void* d_out, int out_size, void* d_ws, size_t ws_size,
                              hipStream_t stream)
{
    const float* data_in = (const float*)d_in[0];
    const float* W1 = (const float*)d_in[1];
    const float* b1 = (const float*)d_in[2];
    const float* W2 = (const float*)d_in[3];
    const float* b2 = (const float*)d_in[4];
    const float* W3 = (const float*)d_in[5];
    const float* b3 = (const float*)d_in[6];
    const float* fWih = (const float*)d_in[7];
    const float* fWhh = (const float*)d_in[8];
    const float* fb = (const float*)d_in[9];
    const float* tWih = (const float*)d_in[10];
    const float* tWhh = (const float*)d_in[11];
    const float* tb = (const float*)d_in[12];
    const float* L1W = (const float*)d_in[13];
    const float* L1b = (const float*)d_in[14];
    const float* L2W = (const float*)d_in[15];
    const float* L2b = (const float*)d_in[16];
    const float* L3W = (const float*)d_in[17];
    const float* L3b = (const float*)d_in[18];
    const float* L4W = (const float*)d_in[19];
    const float* L4b = (const float*)d_in[20];

    float* xseq = (float*)d_ws;            // 4096*180 floats
    float* fv = xseq + 4096 * 180;         // 4096*10 floats
    float* outp = (float*)d_out;           // 64*7 floats

    conv_kernel<<<4096, 256, 0, stream>>>(data_in, W1, b1, W2, b2, W3, b3, xseq);
    flow_lstm_kernel<<<256, 256, 0, stream>>>(xseq, fWih, fWhh, fb, fv);
    trace_mlp_kernel<<<64, 64, 0, stream>>>(fv, tWih, tWhh, tb,
                                            L1W, L1b, L2W, L2b, L3W, L3b,
                                            L4W, L4b, outp);
}

// Round 8
// 196.524 us; speedup vs baseline: 1.0237x; 1.0073x over previous
//
#include <hip/hip_runtime.h>
#include <math.h>

#define LEAK 0.01f

typedef float v2f __attribute__((ext_vector_type(2)));

// opaque pass-through: result of asm cannot be rematerialized by LLVM
#define PIN(x) asm("" : "+v"(x))

__device__ __forceinline__ float lrelu(float x) { return fmaxf(x, LEAK * x); }
__device__ __forceinline__ float fast_rcp(float x) { return __builtin_amdgcn_rcpf(x); }
__device__ __forceinline__ float sigmoid_f(float x) {
    return fast_rcp(1.0f + exp2f(-1.44269504f * x));
}
__device__ __forceinline__ float tanh_f(float x) {
    return 2.0f * fast_rcp(1.0f + exp2f(-2.88539008f * x)) - 1.0f;
}
__device__ __forceinline__ float readlane_f(float v, int l) {
    return __int_as_float(__builtin_amdgcn_readlane(__float_as_int(v), l));
}
__device__ __forceinline__ float bperm_f(int byte_idx, float v) {
    return __int_as_float(__builtin_amdgcn_ds_bpermute(byte_idx, __float_as_int(v)));
}

// ---- named-scalar helpers (NO arrays: guarantees SROA/register residency) ----
#define DECL5(p) v2f p##_0, p##_1, p##_2, p##_3, p##_4
#define LOAD5(p, src) do { const v2f* _s5 = (const v2f*)(src); \
    p##_0 = _s5[0]; p##_1 = _s5[1]; p##_2 = _s5[2]; p##_3 = _s5[3]; p##_4 = _s5[4]; } while (0)
#define CP5(d, s) do { d##_0 = s##_0; d##_1 = s##_1; d##_2 = s##_2; d##_3 = s##_3; d##_4 = s##_4; } while (0)
#define ZERO5(p) do { p##_0 = (v2f){0.f,0.f}; p##_1 = (v2f){0.f,0.f}; p##_2 = (v2f){0.f,0.f}; \
    p##_3 = (v2f){0.f,0.f}; p##_4 = (v2f){0.f,0.f}; } while (0)
// packed dot over 5 v2f pairs (v_pk_fma_f32)
#define DOT5(w, x) ((w##_0 * x##_0 + w##_1 * x##_1) + (w##_2 * x##_2 + w##_3 * x##_3) + w##_4 * x##_4)

// uniform 10-vector as named scalars
#define DECLU(u) float u##0, u##1, u##2, u##3, u##4, u##5, u##6, u##7, u##8, u##9
// dot: VGPR weight pairs x uniform vector
#define DOTU(w, u) (fmaf(w##_0.x, u##0, fmaf(w##_0.y, u##1, fmaf(w##_1.x, u##2, fmaf(w##_1.y, u##3, w##_2.x * u##4)))) \
                  + fmaf(w##_2.y, u##5, fmaf(w##_3.x, u##6, fmaf(w##_3.y, u##7, fmaf(w##_4.x, u##8, w##_4.y * u##9)))))

// 10 weight-pair registers (one v2f per input element)
#define DECLW(p) v2f p##0, p##1, p##2, p##3, p##4, p##5, p##6, p##7, p##8, p##9
#define LOADW_PAIR(p, q0, q1) do { \
    p##0 = (v2f){(q0)[0], (q1)[0]}; p##1 = (v2f){(q0)[1], (q1)[1]}; \
    p##2 = (v2f){(q0)[2], (q1)[2]}; p##3 = (v2f){(q0)[3], (q1)[3]}; \
    p##4 = (v2f){(q0)[4], (q1)[4]}; p##5 = (v2f){(q0)[5], (q1)[5]}; \
    p##6 = (v2f){(q0)[6], (q1)[6]}; p##7 = (v2f){(q0)[7], (q1)[7]}; \
    p##8 = (v2f){(q0)[8], (q1)[8]}; p##9 = (v2f){(q0)[9], (q1)[9]}; } while (0)
#define PINW(p) do { PIN(p##0); PIN(p##1); PIN(p##2); PIN(p##3); PIN(p##4); \
    PIN(p##5); PIN(p##6); PIN(p##7); PIN(p##8); PIN(p##9); } while (0)

#define SP(x) ((v2f){(x), (x)})
// gate-pair pre-activation: bias + Wx·IN + Wh·HD, 4 parallel chains of 5 pk-fma
#define GATES(gRes, wx, wh, bias) \
    v2f gRes; { \
        v2f q0 = bias; \
        q0 += wx##0 * SP(IN0); q0 += wx##2 * SP(IN2); q0 += wx##4 * SP(IN4); \
        q0 += wx##6 * SP(IN6); q0 += wx##8 * SP(IN8); \
        v2f q1 = wx##1 * SP(IN1); \
        q1 += wx##3 * SP(IN3); q1 += wx##5 * SP(IN5); \
        q1 += wx##7 * SP(IN7); q1 += wx##9 * SP(IN9); \
        v2f q2 = wh##0 * SP(HD0); \
        q2 += wh##2 * SP(HD2); q2 += wh##4 * SP(HD4); \
        q2 += wh##6 * SP(HD6); q2 += wh##8 * SP(HD8); \
        v2f q3 = wh##1 * SP(HD1); \
        q3 += wh##3 * SP(HD3); q3 += wh##5 * SP(HD5); \
        q3 += wh##7 * SP(HD7); q3 += wh##9 * SP(HD9); \
        gRes = (q0 + q1) + (q2 + q3); }

#define L1C 508
#define L1P 170
#define L2C 166
#define L2P 56
#define L3C 52
#define L3P 18
#define TT 18

// ---------------------------------------------------------------------------
// K1: per-flow conv1d x3 (+lrelu, +maxpool3 fused) — unchanged.
// ---------------------------------------------------------------------------
__global__ __launch_bounds__(256, 4) void conv_kernel(
    const float* __restrict__ in,
    const float* __restrict__ W1, const float* __restrict__ b1,
    const float* __restrict__ W2, const float* __restrict__ b2,
    const float* __restrict__ W3, const float* __restrict__ b3,
    float* __restrict__ xseq)
{
    __shared__ __align__(16) float xsraw[24 + 1536 + 24];
    __shared__ __align__(16) float y1raw[16 + L1P * 10 + 32];
    __shared__ __align__(16) float y2raw[8 + L2P * 6 + 24];
    float* xs = xsraw + 24;
    float* y1 = y1raw + 16;
    float* y2 = y2raw + 8;

    const int tid = threadIdx.x;
    const int b = blockIdx.x;

    {
        const float4* src = (const float4*)(in + (size_t)b * 1536);
        float4* dst4 = (float4*)xs;
        for (int i = tid; i < 384; i += 256) dst4[i] = src[i];
    }
    __syncthreads();

    // ---- conv1 (3->10, k5) + lrelu + pool3 -> y1[170][10] ----
    {
        const int co = tid % 10;
        const int ob = tid / 10;
        if (tid < 250) {
            float w[15];
            #pragma unroll
            for (int q = 0; q < 15; ++q) w[q] = W1[co * 15 + q];
            const float bias = b1[co];
            const int o0 = ob * 7;
            int sb = 3 * o0 - 1;
            float win[21];
            #pragma unroll
            for (int q = 0; q < 21; ++q) win[q] = xs[3 * sb + q];
            #pragma unroll
            for (int r = 0; r < 7; ++r) {
                const int o = o0 + r;
                if (o < L1P) {
                    float a0 = bias, a1 = bias, a2 = bias;
                    #pragma unroll
                    for (int p = 0; p < 3; ++p) {
                        #pragma unroll
                        for (int k = 0; k < 5; ++k) {
                            const float wv = w[p * 5 + k];
                            a0 = fmaf(wv, win[3 * k + p], a0);
                            a1 = fmaf(wv, win[3 * (k + 1) + p], a1);
                            a2 = fmaf(wv, win[3 * (k + 2) + p], a2);
                        }
                    }
                    float best = -3.0e38f;
                    if (sb >= 0)        best = fmaxf(best, lrelu(a0));
                    best = fmaxf(best, lrelu(a1));
                    if (sb + 2 < L1C)   best = fmaxf(best, lrelu(a2));
                    y1[o * 10 + co] = best;
                }
                if (r < 6 && o + 1 < L1P) {
                    #pragma unroll
                    for (int q = 0; q < 12; ++q) win[q] = win[q + 9];
                    #pragma unroll
                    for (int q = 0; q < 9; ++q) win[12 + q] = xs[3 * sb + 21 + q];
                    sb += 3;
                }
            }
        }
    }
    __syncthreads();

    // ---- conv2 (10->5, k5) + lrelu + pool3 -> y2[56][6-stride] ----
    {
        const int co = tid % 5;
        const int ob = tid / 5;
        v2f wv2[25];
        #pragma unroll
        for (int c2 = 0; c2 < 5; ++c2)
            #pragma unroll
            for (int k = 0; k < 5; ++k)
                wv2[c2 * 5 + k] = (v2f){W2[co * 50 + (2 * c2) * 5 + k],
                                        W2[co * 50 + (2 * c2 + 1) * 5 + k]};
        const float bias = b2[co];
        if (tid < 255) {
            for (int r = 0; r < 2; ++r) {
                const int o = ob + 51 * r;
                if (o < L2P) {
                    const int t0 = 3 * o - 1;
                    v2f v0 = {0.f, 0.f}, v1 = {0.f, 0.f}, v2 = {0.f, 0.f};
                    #pragma unroll
                    for (int m = 0; m < 7; ++m) {
                        v2f rows5[5];
                        const v2f* pr = (const v2f*)(y1 + (t0 + m) * 10);
                        #pragma unroll
                        for (int c2 = 0; c2 < 5; ++c2) rows5[c2] = pr[c2];
                        #pragma unroll
                        for (int c2 = 0; c2 < 5; ++c2) {
                            if (m < 5)            v0 += wv2[c2 * 5 + m] * rows5[c2];
                            if (m >= 1 && m <= 5) v1 += wv2[c2 * 5 + m - 1] * rows5[c2];
                            if (m >= 2)           v2 += wv2[c2 * 5 + m - 2] * rows5[c2];
                        }
                    }
                    const float a0 = bias + v0.x + v0.y;
                    const float a1 = bias + v1.x + v1.y;
                    const float a2 = bias + v2.x + v2.y;
                    float best = -3.0e38f;
                    if (t0 >= 0)        best = fmaxf(best, lrelu(a0));
                    best = fmaxf(best, lrelu(a1));
                    if (t0 + 2 < L2C)   best = fmaxf(best, lrelu(a2));
                    y2[o * 6 + co] = best;
                }
            }
        }
    }
    __syncthreads();

    // ---- conv3 (5->10, k5) + lrelu + pool3 -> xseq ----
    {
        const int co = tid % 10;
        const int o = tid / 10;
        if (o < L3P) {
            v2f wv3[10];
            float ws3[5];
            #pragma unroll
            for (int c2 = 0; c2 < 2; ++c2)
                #pragma unroll
                for (int k = 0; k < 5; ++k)
                    wv3[c2 * 5 + k] = (v2f){W3[co * 25 + (2 * c2) * 5 + k],
                                            W3[co * 25 + (2 * c2 + 1) * 5 + k]};
            #pragma unroll
            for (int k = 0; k < 5; ++k) ws3[k] = W3[co * 25 + 20 + k];
            const float bias = b3[co];
            const int t0 = 3 * o - 1;
            v2f v0 = {0.f, 0.f}, v1 = {0.f, 0.f}, v2 = {0.f, 0.f};
            float s0 = 0.f, s1 = 0.f, s2 = 0.f;
            #pragma unroll
            for (int m = 0; m < 7; ++m) {
                const float* base = y2 + (t0 + m) * 6;
                v2f ra0 = ((const v2f*)base)[0];
                v2f ra1 = ((const v2f*)base)[1];
                float rcm = base[4];
                if (m < 5) {
                    v0 += wv3[m] * ra0; v0 += wv3[5 + m] * ra1;
                    s0 = fmaf(ws3[m], rcm, s0);
                }
                if (m >= 1 && m <= 5) {
                    v1 += wv3[m - 1] * ra0; v1 += wv3[5 + m - 1] * ra1;
                    s1 = fmaf(ws3[m - 1], rcm, s1);
                }
                if (m >= 2) {
                    v2 += wv3[m - 2] * ra0; v2 += wv3[5 + m - 2] * ra1;
                    s2 = fmaf(ws3[m - 2], rcm, s2);
                }
            }
            const float a0 = bias + s0 + v0.x + v0.y;
            const float a1 = bias + s1 + v1.x + v1.y;
            const float a2 = bias + s2 + v2.x + v2.y;
            float best = -3.0e38f;
            if (t0 >= 0)        best = fmaxf(best, lrelu(a0));
            best = fmaxf(best, lrelu(a1));
            if (t0 + 2 < L3C)   best = fmaxf(best, lrelu(a2));
            xseq[(size_t)b * 180 + o * 10 + co] = best;
        }
    }
}

// ---------------------------------------------------------------------------
// K2: flow LSTM — unchanged from R7.
// ---------------------------------------------------------------------------
__global__ __launch_bounds__(256) __attribute__((amdgpu_waves_per_eu(1, 1)))
void flow_lstm_kernel(
    const float* __restrict__ xseq,
    const float* __restrict__ fWih, const float* __restrict__ fWhh,
    const float* __restrict__ fb,
    float* __restrict__ fv)
{
    __shared__ __align__(16) float sbuf[3][16 * 18 * 10];
    const int tid = threadIdx.x;
    const int blk = blockIdx.x;

    {
        const float* src = xseq + (size_t)blk * 2880;
        for (int i = tid; i < 2880; i += 256) sbuf[0][i] = src[i];
    }
    __syncthreads();

    const int el = tid >> 4;
    const int j = tid & 15;
    const int jj = (j < 10) ? j : 0;
    const int base = el * 180;
    const int lane = tid & 63;
    const int gbase = lane & 48;

    float fv_acc = 0.0f;

    for (int l = 0; l < 3; ++l) {
        const float* Wi = fWih + l * 400;
        const float* Wh = fWhh + l * 400;
        const float* bb = fb + l * 40;
        DECL5(wii); DECL5(wif); DECL5(wig); DECL5(wio);
        DECL5(whi); DECL5(whf); DECL5(whg); DECL5(who);
        LOAD5(wii, Wi + jj * 10);
        LOAD5(wif, Wi + (10 + jj) * 10);
        LOAD5(wig, Wi + (20 + jj) * 10);
        LOAD5(wio, Wi + (30 + jj) * 10);
        LOAD5(whi, Wh + jj * 10);
        LOAD5(whf, Wh + (10 + jj) * 10);
        LOAD5(whg, Wh + (20 + jj) * 10);
        LOAD5(who, Wh + (30 + jj) * 10);
        const float bi = bb[jj], bf = bb[10 + jj], bg = bb[20 + jj], bo = bb[30 + jj];

        const float* inb = sbuf[l];
        float* outb = sbuf[(l + 1) % 3];
        float c = 0.0f, hj = 0.0f;
        DECL5(hv); ZERO5(hv);
        DECL5(xc); DECL5(xn);
        LOAD5(xc, inb + base);

        for (int t = 0; t < TT; ++t) {
            if (t + 1 < TT) LOAD5(xn, inb + base + (t + 1) * 10);
            v2f ti_ = DOT5(wii, xc) + DOT5(whi, hv);
            v2f tf_ = DOT5(wif, xc) + DOT5(whf, hv);
            v2f tg_ = DOT5(wig, xc) + DOT5(whg, hv);
            v2f to_ = DOT5(wio, xc) + DOT5(who, hv);
            const float ai = sigmoid_f(bi + ti_.x + ti_.y);
            const float af = sigmoid_f(bf + tf_.x + tf_.y);
            const float ag = tanh_f(bg + tg_.x + tg_.y);
            const float ao = sigmoid_f(bo + to_.x + to_.y);
            c = af * c + ai * ag;
            hj = ao * tanh_f(c);
            if (j < 10) outb[base + t * 10 + j] = hj;
            hv_0 = (v2f){__shfl(hj, gbase + 0), __shfl(hj, gbase + 1)};
            hv_1 = (v2f){__shfl(hj, gbase + 2), __shfl(hj, gbase + 3)};
            hv_2 = (v2f){__shfl(hj, gbase + 4), __shfl(hj, gbase + 5)};
            hv_3 = (v2f){__shfl(hj, gbase + 6), __shfl(hj, gbase + 7)};
            hv_4 = (v2f){__shfl(hj, gbase + 8), __shfl(hj, gbase + 9)};
            CP5(xc, xn);
        }
        if (l >= 1) fv_acc += hj;
        __asm__ __volatile__("" ::: "memory");
    }
    if (j < 10) fv[(size_t)(blk * 16 + el) * 10 + j] = fv_acc;
}

// ---------------------------------------------------------------------------
// K3: trace LSTM (3 layers, T=64, H=10), one wave per trace row, + fused MLP.
// Per-lane VGPR state, propagated by fixed-pattern ds_bpermute (no SGPR
// round-trip, no cndmask re-selects): lane g*10+j holds its layer's input
// vector IN0..9 and hidden vector HD0..9 as VGPRs; after the lane-local
// cell update, 20 bpermutes regenerate both from h. x lives in a register
// file (lane t holds x[t][0..9]); layer0's input enters via 10 off-chain
// readlanes + cndmask into lanes 0-9.
// ---------------------------------------------------------------------------
__global__ __launch_bounds__(64) __attribute__((amdgpu_waves_per_eu(1, 1)))
void trace_mlp_kernel(
    const float* __restrict__ fv,
    const float* __restrict__ tWih, const float* __restrict__ tWhh,
    const float* __restrict__ tb,
    const float* __restrict__ L1W, const float* __restrict__ L1b,
    const float* __restrict__ L2W, const float* __restrict__ L2b,
    const float* __restrict__ L3W, const float* __restrict__ L3b,
    const float* __restrict__ L4W, const float* __restrict__ L4b,
    float* __restrict__ out)
{
    __shared__ __align__(16) float m1[128];
    __shared__ __align__(16) float m2b[256];
    __shared__ __align__(16) float m3[64];

    const int lane = threadIdx.x;
    const int ti = blockIdx.x;
    const int g = (lane < 30) ? (lane / 10) : 2;   // layer this lane serves
    const int j = lane % 10;                        // hidden unit
    const bool isL0 = (lane < 10);

    // x register file: lane t holds x[t][0..9] (t = lane, 64 lanes = 64 steps)
    float xr0, xr1, xr2, xr3, xr4, xr5, xr6, xr7, xr8, xr9;
    {
        const float2* xp = (const float2*)(fv + (size_t)ti * 640 + lane * 10);
        float2 v0 = xp[0], v1 = xp[1], v2 = xp[2], v3 = xp[3], v4 = xp[4];
        xr0 = v0.x; xr1 = v0.y; xr2 = v1.x; xr3 = v1.y; xr4 = v2.x;
        xr5 = v2.y; xr6 = v3.x; xr7 = v3.y; xr8 = v4.x; xr9 = v4.y;
    }
    PIN(xr0); PIN(xr1); PIN(xr2); PIN(xr3); PIN(xr4);
    PIN(xr5); PIN(xr6); PIN(xr7); PIN(xr8); PIN(xr9);

    // weight pairs for this lane's layer/unit: A=(i,f), B=(g,o)
    const float* WiL = tWih + g * 400;
    const float* WhL = tWhh + g * 400;
    const float* bL  = tb + g * 40;
    DECLW(wxA); DECLW(wxB); DECLW(whA); DECLW(whB);
    LOADW_PAIR(wxA, WiL + j * 10,        WiL + (10 + j) * 10);
    LOADW_PAIR(wxB, WiL + (20 + j) * 10, WiL + (30 + j) * 10);
    LOADW_PAIR(whA, WhL + j * 10,        WhL + (10 + j) * 10);
    LOADW_PAIR(whB, WhL + (20 + j) * 10, WhL + (30 + j) * 10);
    v2f bA = (v2f){bL[j], bL[10 + j]};
    v2f bB = (v2f){bL[20 + j], bL[30 + j]};
    PINW(wxA); PINW(wxB); PINW(whA); PINW(whB);
    PIN(bA); PIN(bB);

    // bpermute byte bases: HD from own layer's lanes, IN from previous layer's
    const int idx_hd = g * 40;
    const int idx_in = (g == 0) ? 0 : (g - 1) * 40;   // g=0 garbage, overwritten

    // per-lane state
    float HD0 = 0.f, HD1 = 0.f, HD2 = 0.f, HD3 = 0.f, HD4 = 0.f;
    float HD5 = 0.f, HD6 = 0.f, HD7 = 0.f, HD8 = 0.f, HD9 = 0.f;
    float IN0 = isL0 ? readlane_f(xr0, 0) : 0.f;
    float IN1 = isL0 ? readlane_f(xr1, 0) : 0.f;
    float IN2 = isL0 ? readlane_f(xr2, 0) : 0.f;
    float IN3 = isL0 ? readlane_f(xr3, 0) : 0.f;
    float IN4 = isL0 ? readlane_f(xr4, 0) : 0.f;
    float IN5 = isL0 ? readlane_f(xr5, 0) : 0.f;
    float IN6 = isL0 ? readlane_f(xr6, 0) : 0.f;
    float IN7 = isL0 ? readlane_f(xr7, 0) : 0.f;
    float IN8 = isL0 ? readlane_f(xr8, 0) : 0.f;
    float IN9 = isL0 ? readlane_f(xr9, 0) : 0.f;
    float c = 0.0f, h = 0.0f;

    for (int tau = 0; tau < 66; ++tau) {
        const int tn = (tau + 1 < 64) ? (tau + 1) : 63;
        // off-chain: next-tick x as uniforms
        const float nx0 = readlane_f(xr0, tn);
        const float nx1 = readlane_f(xr1, tn);
        const float nx2 = readlane_f(xr2, tn);
        const float nx3 = readlane_f(xr3, tn);
        const float nx4 = readlane_f(xr4, tn);
        const float nx5 = readlane_f(xr5, tn);
        const float nx6 = readlane_f(xr6, tn);
        const float nx7 = readlane_f(xr7, tn);
        const float nx8 = readlane_f(xr8, tn);
        const float nx9 = readlane_f(xr9, tn);

        GATES(gA, wxA, whA, bA);
        GATES(gB, wxB, whB, bB);

        const float ai = sigmoid_f(gA.x);
        const float af = sigmoid_f(gA.y);
        const float ag = tanh_f(gB.x);
        const float ao = sigmoid_f(gB.y);
        const float cn = af * c + ai * ag;
        const float hn = ao * tanh_f(cn);
        const bool act = (tau >= g) && (tau - g <= 63);
        c = act ? cn : c;
        h = act ? hn : h;

        // one DS round: regenerate HD and IN from committed h (fixed patterns)
        HD0 = bperm_f(idx_hd + 0,  h);
        HD1 = bperm_f(idx_hd + 4,  h);
        HD2 = bperm_f(idx_hd + 8,  h);
        HD3 = bperm_f(idx_hd + 12, h);
        HD4 = bperm_f(idx_hd + 16, h);
        HD5 = bperm_f(idx_hd + 20, h);
        HD6 = bperm_f(idx_hd + 24, h);
        HD7 = bperm_f(idx_hd + 28, h);
        HD8 = bperm_f(idx_hd + 32, h);
        HD9 = bperm_f(idx_hd + 36, h);
        const float i0 = bperm_f(idx_in + 0,  h);
        const float i1 = bperm_f(idx_in + 4,  h);
        const float i2 = bperm_f(idx_in + 8,  h);
        const float i3 = bperm_f(idx_in + 12, h);
        const float i4 = bperm_f(idx_in + 16, h);
        const float i5 = bperm_f(idx_in + 20, h);
        const float i6 = bperm_f(idx_in + 24, h);
        const float i7 = bperm_f(idx_in + 28, h);
        const float i8 = bperm_f(idx_in + 32, h);
        const float i9 = bperm_f(idx_in + 36, h);
        IN0 = isL0 ? nx0 : i0;
        IN1 = isL0 ? nx1 : i1;
        IN2 = isL0 ? nx2 : i2;
        IN3 = isL0 ? nx3 : i3;
        IN4 = isL0 ? nx4 : i4;
        IN5 = isL0 ? nx5 : i5;
        IN6 = isL0 ? nx6 : i6;
        IN7 = isL0 ? nx7 : i7;
        IN8 = isL0 ? nx8 : i8;
        IN9 = isL0 ? nx9 : i9;
    }

    // tv = h_n(layer2) + h_n(layer1): uniform
    DECLU(tv);
    tv0 = readlane_f(h, 10) + readlane_f(h, 20);
    tv1 = readlane_f(h, 11) + readlane_f(h, 21);
    tv2 = readlane_f(h, 12) + readlane_f(h, 22);
    tv3 = readlane_f(h, 13) + readlane_f(h, 23);
    tv4 = readlane_f(h, 14) + readlane_f(h, 24);
    tv5 = readlane_f(h, 15) + readlane_f(h, 25);
    tv6 = readlane_f(h, 16) + readlane_f(h, 26);
    tv7 = readlane_f(h, 17) + readlane_f(h, 27);
    tv8 = readlane_f(h, 18) + readlane_f(h, 28);
    tv9 = readlane_f(h, 19) + readlane_f(h, 29);

    // ---- fused per-row MLP: 10 ->128 ->256 ->64 ->7 ----
    {
        DECL5(w1a); DECL5(w1b);
        LOAD5(w1a, L1W + lane * 10);
        LOAD5(w1b, L1W + (lane + 64) * 10);
        float a0 = L1b[lane] + DOTU(w1a, tv);
        float a1 = L1b[lane + 64] + DOTU(w1b, tv);
        m1[lane] = lrelu(a0);
        m1[lane + 64] = lrelu(a1);
    }
    __asm__ __volatile__("" ::: "memory");
    {
        float acc0 = L2b[lane];
        float acc1 = L2b[lane + 64];
        float acc2 = L2b[lane + 128];
        float acc3 = L2b[lane + 192];
        for (int k = 0; k < 128; k += 4) {
            float4 hv = *(const float4*)(m1 + k);
            float4 w0 = *(const float4*)(L2W + (size_t)lane * 128 + k);
            float4 w1 = *(const float4*)(L2W + (size_t)(lane + 64) * 128 + k);
            float4 w2 = *(const float4*)(L2W + (size_t)(lane + 128) * 128 + k);
            float4 w3 = *(const float4*)(L2W + (size_t)(lane + 192) * 128 + k);
            acc0 = fmaf(w0.x, hv.x, acc0); acc0 = fmaf(w0.y, hv.y, acc0);
            acc0 = fmaf(w0.z, hv.z, acc0); acc0 = fmaf(w0.w, hv.w, acc0);
            acc1 = fmaf(w1.x, hv.x, acc1); acc1 = fmaf(w1.y, hv.y, acc1);
            acc1 = fmaf(w1.z, hv.z, acc1); acc1 = fmaf(w1.w, hv.w, acc1);
            acc2 = fmaf(w2.x, hv.x, acc2); acc2 = fmaf(w2.y, hv.y, acc2);
            acc2 = fmaf(w2.z, hv.z, acc2); acc2 = fmaf(w2.w, hv.w, acc2);
            acc3 = fmaf(w3.x, hv.x, acc3); acc3 = fmaf(w3.y, hv.y, acc3);
            acc3 = fmaf(w3.z, hv.z, acc3); acc3 = fmaf(w3.w, hv.w, acc3);
        }
        m2b[lane] = lrelu(acc0);
        m2b[lane + 64] = lrelu(acc1);
        m2b[lane + 128] = lrelu(acc2);
        m2b[lane + 192] = lrelu(acc3);
    }
    __asm__ __volatile__("" ::: "memory");
    {
        float acc = L3b[lane];
        for (int k = 0; k < 256; k += 4) {
            float4 hv = *(const float4*)(m2b + k);
            float4 wv = *(const float4*)(L3W + (size_t)lane * 256 + k);
            acc = fmaf(wv.x, hv.x, acc);
            acc = fmaf(wv.y, hv.y, acc);
            acc = fmaf(wv.z, hv.z, acc);
            acc = fmaf(wv.w, hv.w, acc);
        }
        m3[lane] = lrelu(acc);
    }
    __asm__ __volatile__("" ::: "memory");
    if (lane < 7) {
        float acc = L4b[lane];
        #pragma unroll
        for (int k = 0; k < 64; k += 4) {
            float4 hv = *(const float4*)(m3 + k);
            float4 wv = *(const float4*)(L4W + lane * 64 + k);
            acc = fmaf(wv.x, hv.x, acc);
            acc = fmaf(wv.y, hv.y, acc);
            acc = fmaf(wv.z, hv.z, acc);
            acc = fmaf(wv.w, hv.w, acc);
        }
        out[ti * 7 + lane] = acc;
    }
}

// ---------------------------------------------------------------------------
extern "C" void kernel_launch(void* const* d_in, const int* in_sizes, int n_in,
                              void* d_out, int out_size, void* d_ws, size_t ws_size,
                              hipStream_t stream)
{
    const float* data_in = (const float*)d_in[0];
    const float* W1 = (const float*)d_in[1];
    const float* b1 = (const float*)d_in[2];
    const float* W2 = (const float*)d_in[3];
    const float* b2 = (const float*)d_in[4];
    const float* W3 = (const float*)d_in[5];
    const float* b3 = (const float*)d_in[6];
    const float* fWih = (const float*)d_in[7];
    const float* fWhh = (const float*)d_in[8];
    const float* fb = (const float*)d_in[9];
    const float* tWih = (const float*)d_in[10];
    const float* tWhh = (const float*)d_in[11];
    const float* tb = (const float*)d_in[12];
    const float* L1W = (const float*)d_in[13];
    const float* L1b = (const float*)d_in[14];
    const float* L2W = (const float*)d_in[15];
    const float* L2b = (const float*)d_in[16];
    const float* L3W = (const float*)d_in[17];
    const float* L3b = (const float*)d_in[18];
    const float* L4W = (const float*)d_in[19];
    const float* L4b = (const float*)d_in[20];

    float* xseq = (float*)d_ws;            // 4096*180 floats
    float* fv = xseq + 4096 * 180;         // 4096*10 floats
    float* outp = (float*)d_out;           // 64*7 floats

    conv_kernel<<<4096, 256, 0, stream>>>(data_in, W1, b1, W2, b2, W3, b3, xseq);
    flow_lstm_kernel<<<256, 256, 0, stream>>>(xseq, fWih, fWhh, fb, fv);
    trace_mlp_kernel<<<64, 64, 0, stream>>>(fv, tWih, tWhh, tb,
                                            L1W, L1b, L2W, L2b, L3W, L3b,
                                            L4W, L4b, outp);
}